// Round 7
// baseline (857.877 us; speedup 1.0000x reference)
//
#include <hip/hip_runtime.h>
#include <math.h>

#define B_    2
#define S_    2048
#define H_    2048
#define NH_   16
#define NOPE_ 128
#define ROPE_ 64
#define VDIM_ 128
#define RANK_ 512
#define QHD_  192   // NOPE + ROPE
#define DTOT_ 576   // RANK + ROPE

typedef short short8 __attribute__((ext_vector_type(8)));
typedef float f32x4 __attribute__((ext_vector_type(4)));

__device__ __forceinline__ unsigned short f2bf(float f) {
    unsigned u = __float_as_uint(f);
    u += 0x7fffu + ((u >> 16) & 1u);
    return (unsigned short)(u >> 16);
}
__device__ __forceinline__ float bf2f(unsigned short u) {
    return __uint_as_float((unsigned)u << 16);
}
__device__ __forceinline__ unsigned pack2bf(float a, float b) {
    return (unsigned)f2bf(a) | ((unsigned)f2bf(b) << 16);
}
__device__ __forceinline__ unsigned long long pack4bf(float a, float b, float c, float d) {
    return (unsigned long long)pack2bf(a, b) | ((unsigned long long)pack2bf(c, d) << 32);
}
union i4s8 { int4 i; short8 s; };

// Async global->LDS, 16B per lane. LDS dest = wave-uniform base + lane*16.
typedef __attribute__((address_space(3))) unsigned int lds_u32_t;
typedef __attribute__((address_space(1))) const unsigned int glob_u32_t;
__device__ __forceinline__ void async_copy16(const unsigned short* g, unsigned short* l) {
    __builtin_amdgcn_global_load_lds((glob_u32_t*)g, (lds_u32_t*)l, 16, 0, 0);
}

// ---------------------------------------------------------------------------
// cast fp32 -> bf16, 4 elems/thread.
// ---------------------------------------------------------------------------
__global__ __launch_bounds__(256) void cast_bf16(const float* __restrict__ in,
                                                 unsigned short* __restrict__ out)
{
    const size_t i = ((size_t)blockIdx.x * 256 + threadIdx.x) * 4;
    float4 v = *(const float4*)(in + i);
    *(unsigned long long*)(out + i) = pack4bf(v.x, v.y, v.z, v.w);
}

// ---------------------------------------------------------------------------
// Transpose + cast: in fp32 [Rr][Cc] (batched) -> out bf16 [Cc][Rr].
// grid (Rr/64, Cc/64, batch), 256 threads.
// ---------------------------------------------------------------------------
__global__ __launch_bounds__(256) void transpose_w(const float* __restrict__ in,
                                                   unsigned short* __restrict__ out,
                                                   int Rr, int Cc,
                                                   size_t inBatch, size_t outBatch)
{
    __shared__ unsigned short tl[64][72];
    in  += (size_t)blockIdx.z * inBatch;
    out += (size_t)blockIdx.z * outBatch;
    const int t  = threadIdx.x;
    const int r0 = blockIdx.x * 64;
    const int c0 = blockIdx.y * 64;
    const int lr = t >> 4;
    const int lc = (t & 15) * 4;
#pragma unroll
    for (int r = 0; r < 4; ++r) {
        float4 v = *(const float4*)(in + (size_t)(r0 + lr*4 + r) * Cc + c0 + lc);
        tl[lr*4 + r][lc+0] = f2bf(v.x); tl[lr*4 + r][lc+1] = f2bf(v.y);
        tl[lr*4 + r][lc+2] = f2bf(v.z); tl[lr*4 + r][lc+3] = f2bf(v.w);
    }
    __syncthreads();
#pragma unroll
    for (int r = 0; r < 4; ++r) {
        ushort4 v;
        v.x = tl[lc+0][lr*4+r]; v.y = tl[lc+1][lr*4+r];
        v.z = tl[lc+2][lr*4+r]; v.w = tl[lc+3][lr*4+r];
        *(ushort4*)(out + (size_t)(c0 + lr*4 + r) * Rr + r0 + lc) = v;
    }
}

// ---------------------------------------------------------------------------
// bf16 MFMA GEMM, m97-style: C = A[M][K](lda) @ Bt^T, Bt bf16 [N][K](ldb).
// 128x128 tile, 4 waves, BK=32, global_load_lds staging. N-guard for ragged N.
// mode 1: batched q-absorb. mode 2: batched VW^T = out_absorb @ k_cat^T.
// ---------------------------------------------------------------------------
#define BGEMM_BODY(STORE_STMT)                                                     \
    __shared__ unsigned short Al[128*32];                                          \
    __shared__ unsigned short Bl[128*32];                                          \
    const int t = threadIdx.x;                                                     \
    const int wv = t >> 6;                                                         \
    const int lane = t & 63;                                                       \
    const int lq = lane & 15, quad = lane >> 4;                                    \
    const int m0 = blockIdx.y * 128, n0 = blockIdx.x * 128;                        \
    const int wrow = (wv >> 1) * 64, wcol = (wv & 1) * 64;                         \
    const int srow = lane >> 2;                                                    \
    const int scol = (lane & 3) * 8;                                               \
    f32x4 acc[4][4] = {};                                                          \
    for (int k0 = 0; k0 < K; k0 += 32) {                                           \
        _Pragma("unroll")                                                          \
        for (int pA = 0; pA < 2; ++pA) {                                           \
            const unsigned short* src =                                            \
                A + (size_t)(m0 + pA*64 + wv*16 + srow) * lda + k0 + scol;         \
            async_copy16(src, &Al[pA*2048 + wv*512]);                              \
        }                                                                          \
        _Pragma("unroll")                                                          \
        for (int pB = 0; pB < 2; ++pB) {                                           \
            int brow = n0 + pB*64 + wv*16 + srow;                                  \
            if (brow > N - 1) brow = N - 1;                                        \
            const unsigned short* src = B + (size_t)brow * ldb + k0 + scol;        \
            async_copy16(src, &Bl[pB*2048 + wv*512]);                              \
        }                                                                          \
        __syncthreads();                                                           \
        short8 af[4], bf[4];                                                       \
        _Pragma("unroll")                                                          \
        for (int i = 0; i < 4; ++i) {                                              \
            af[i] = *(const short8*)&Al[(wrow + i*16 + lq)*32 + quad*8];           \
            bf[i] = *(const short8*)&Bl[(wcol + i*16 + lq)*32 + quad*8];           \
        }                                                                          \
        _Pragma("unroll")                                                          \
        for (int mi = 0; mi < 4; ++mi)                                             \
            _Pragma("unroll")                                                      \
            for (int ni = 0; ni < 4; ++ni)                                         \
                acc[mi][ni] = __builtin_amdgcn_mfma_f32_16x16x32_bf16(             \
                    af[mi], bf[ni], acc[mi][ni], 0, 0, 0);                         \
        __syncthreads();                                                           \
    }                                                                              \
    _Pragma("unroll")                                                              \
    for (int mi = 0; mi < 4; ++mi)                                                 \
        _Pragma("unroll")                                                          \
        for (int ni = 0; ni < 4; ++ni) {                                           \
            int col = n0 + wcol + ni*16 + lq;                                      \
            if (col < N) {                                                         \
                _Pragma("unroll")                                                  \
                for (int r = 0; r < 4; ++r)                                       \
                    STORE_STMT;                                                    \
            }                                                                      \
        }

__global__ __launch_bounds__(256, 2) void bgemm2(const unsigned short* __restrict__ A,
                                                 int lda,
                                                 const unsigned short* __restrict__ B,
                                                 int ldb,
                                                 unsigned short* __restrict__ C,
                                                 int ldc, int K, int N, int qcmode)
{
    if (qcmode == 1) {
        const int z = blockIdx.z;
        A += (size_t)(z >> 4) * S_ * (NH_*QHD_) + (z & 15) * QHD_;
        B += (size_t)(z & 15) * RANK_ * NOPE_;
        C += (size_t)z * S_ * DTOT_;
    } else if (qcmode == 2) {
        // VW^T[b,h] [128][2048] = out_absorb[h] [128][512] @ (k_cat[b][:, :512])^T
        const int z = blockIdx.z;
        A += (size_t)(z & 15) * 256 * RANK_ + (size_t)NOPE_ * RANK_;
        B += (size_t)(z >> 4) * S_ * DTOT_;
        C += (size_t)z * VDIM_ * S_;
    }
    BGEMM_BODY(C[(size_t)(m0 + wrow + mi*16 + quad*4 + r) * ldc + col] = f2bf(acc[mi][ni][r]))
}

__global__ __launch_bounds__(256, 2) void bgemm2f(const unsigned short* __restrict__ A,
                                                  int lda,
                                                  const unsigned short* __restrict__ B,
                                                  int ldb,
                                                  float* __restrict__ C,
                                                  int ldc, int K, int N)
{
    BGEMM_BODY(C[(size_t)(m0 + wrow + mi*16 + quad*4 + r) * ldc + col] = acc[mi][ni][r])
}

// ---------------------------------------------------------------------------
// Per (b,s) row: RMSNorm ckv (bf16 in) -> k_cat[0:512]; RoPE k_pe -> [512:576].
// ---------------------------------------------------------------------------
__global__ __launch_bounds__(128) void postkv(const unsigned short* __restrict__ ckv_bf,
                                              const float* __restrict__ lnw,
                                              const int*   __restrict__ pos_ids,
                                              const float* __restrict__ cosc,
                                              const float* __restrict__ sinc,
                                              unsigned short* __restrict__ k_cat)
{
    const int row = blockIdx.x;
    const int t   = threadIdx.x;
    const unsigned short* src = ckv_bf + (size_t)row * DTOT_;
    __shared__ float red[128];

    ushort4 v = *(const ushort4*)(src + t * 4);
    float x0 = bf2f(v.x), x1 = bf2f(v.y), x2 = bf2f(v.z), x3 = bf2f(v.w);
    red[t] = x0*x0 + x1*x1 + x2*x2 + x3*x3;
    __syncthreads();
    for (int off = 64; off > 0; off >>= 1) {
        if (t < off) red[t] += red[t + off];
        __syncthreads();
    }
    const float rs = rsqrtf(red[0] / (float)RANK_ + 1e-6f);

    unsigned short* kc = k_cat + (size_t)row * DTOT_;
    *(unsigned long long*)(kc + t*4) =
        pack4bf(x0*rs*lnw[t*4+0], x1*rs*lnw[t*4+1], x2*rs*lnw[t*4+2], x3*rs*lnw[t*4+3]);

    if (t < 32) {
        const int pos = pos_ids[row];
        const float c  = cosc[pos * ROPE_ + t];
        const float sn = sinc[pos * ROPE_ + t];
        const float y0 = bf2f(src[RANK_ + 2*t]);
        const float y1 = bf2f(src[RANK_ + 2*t + 1]);
        kc[RANK_ + t]      = f2bf(y0*c - y1*sn);
        kc[RANK_ + 32 + t] = f2bf(y1*c + y0*sn);
    }
}

// ---------------------------------------------------------------------------
// RoPE q_pe (bf16 in) -> q_cat[...,512:576]. grid = B*S, 512 threads.
// ---------------------------------------------------------------------------
__global__ __launch_bounds__(512) void ropeq(const unsigned short* __restrict__ q_bf,
                                             const int*   __restrict__ pos_ids,
                                             const float* __restrict__ cosc,
                                             const float* __restrict__ sinc,
                                             unsigned short* __restrict__ q_cat)
{
    const int row = blockIdx.x;
    const int t   = threadIdx.x;
    const int h   = t >> 5;
    const int i   = t & 31;
    const int pos = pos_ids[row];
    const float c  = cosc[pos * ROPE_ + i];
    const float sn = sinc[pos * ROPE_ + i];
    const unsigned short* qrow = q_bf + (size_t)row * (NH_*QHD_) + h * QHD_ + NOPE_;
    const float x0 = bf2f(qrow[2*i]);
    const float x1 = bf2f(qrow[2*i + 1]);
    const int b = row >> 11, s = row & 2047;
    unsigned short* qc = q_cat + ((size_t)(b * NH_ + h) * S_ + s) * DTOT_ + RANK_;
    qc[i]      = f2bf(x0*c - x1*sn);
    qc[32 + i] = f2bf(x1*c + x0*sn);
}

__global__ __launch_bounds__(256) void wcast(const float* __restrict__ w,
                                             unsigned short* __restrict__ wbf)
{
    const size_t i = ((size_t)blockIdx.x * 256 + threadIdx.x) * 4;
    float4 v = *(const float4*)(w + i);
    *(unsigned long long*)(wbf + i) = pack4bf(v.x, v.y, v.z, v.w);
}

// ---------------------------------------------------------------------------
// Flash attention v10: 32 q-rows/wave (2 groups), BOTH Q groups streamed from
// L2 each tile. v9 spilled (WRITE 40MB) because q1row is tt-invariant -> LICM
// hoisted 18 streamed loads into 144 persistent VGPRs over the 128 cap.
// v10 defeats LICM with an opaque-pointer asm per tile iteration (compiler
// must assume the pointer changes, so loads can't be hoisted out of tt).
// No persistent Q: peak arch-VGPR ~100. Q slice (147KB/block) stays L2-hot;
// extra L2 read traffic ~2.5GB over the kernel (~23 TB/s, under 34.5 ceiling).
// Everything else (K/V DMA schedule, swizzles, defer-max) identical to v9.
// ---------------------------------------------------------------------------
__device__ __forceinline__ short8 quad_transpose(unsigned d0, unsigned d1,
                                                 unsigned d2, unsigned d3,
                                                 int srcA, int srcB, bool lowquad)
{
    int e0 = __shfl((int)d0, srcA, 64);
    int e1 = __shfl((int)d1, srcA, 64);
    int e2 = __shfl((int)d2, srcA, 64);
    int e3 = __shfl((int)d3, srcA, 64);
    int f0 = __shfl((int)d0, srcB, 64);
    int f1 = __shfl((int)d1, srcB, 64);
    int f2 = __shfl((int)d2, srcB, 64);
    int f3 = __shfl((int)d3, srcB, 64);
    i4s8 u;
    u.i.x = lowquad ? e0 : e2;
    u.i.y = lowquad ? e1 : e3;
    u.i.z = lowquad ? f0 : f2;
    u.i.w = lowquad ? f1 : f3;
    return u.s;
}

__global__ __launch_bounds__(256, 2) void flash_attn4(
    const unsigned short* __restrict__ q_cat,
    const unsigned short* __restrict__ k_cat,
    const unsigned short* __restrict__ vwt,
    unsigned short* __restrict__ attn_bf)
{
    __shared__ unsigned short sKa[32*512];   // 32768 B, RANK part, swizzled
    __shared__ unsigned short sKb[32*64];    //  4096 B, RoPE part, swizzled
    __shared__ unsigned short sVW[128*32];   //  8192 B, VW^T tile, swizzled

    const int t    = threadIdx.x;
    const int wv   = t >> 6;
    const int lane = t & 63;
    const int lq   = lane & 15;
    const int quad = lane >> 4;
    const int h    = blockIdx.x;
    const int b    = blockIdx.z;
    // anti-paired strip lengths: b0 longest-first, b1 reversed (const per-CU sum)
    const int ystrip = b ? blockIdx.y : (15 - blockIdx.y);
    const int q0   = ystrip * 128;
    const int srcA = lq + ((quad & 1) << 5);
    const int srcB = srcA + 16;
    const bool lowq = quad < 2;
    const int myq0 = q0 + wv*16 + lq;        // group0 row; group1 = +64

    // Q row base (both groups streamed from L2 inside the tile loop)
    const unsigned short* qrow =
        q_cat + (((size_t)(b*NH_ + h)) * S_ + q0 + wv*16 + lq) * DTOT_ + quad*8;

    const unsigned short* kcb = k_cat + (size_t)b * S_ * DTOT_;
    const unsigned short* vtb = vwt + (size_t)(b*NH_ + h) * VDIM_ * S_;

    f32x4 o0[8], o1[8];
#pragma unroll
    for (int i = 0; i < 8; ++i) {
        o0[i] = (f32x4){0.f, 0.f, 0.f, 0.f};
        o1[i] = (f32x4){0.f, 0.f, 0.f, 0.f};
    }
    float mi0 = -1e30f, li0 = 0.f, mi1 = -1e30f, li1 = 0.f;
    const float scale = 0.0721687836f;  // 1/sqrt(192)
    const int ntiles = (q0 >> 5) + 4;

    // --- K read-side swizzle: logical granule (row, g) lives at physical
    // g^(row&7); rows lq and 16+lq share (lq&7).
    const int swz  = lq & 7;
    const int selA = (swz >> 2) * 32;           // shorts: +32 if bit2 of swz
    const int selB = 32 - selA;
    const int kqo  = (quad ^ (swz & 3)) * 8;    // shorts within 128B block
    const unsigned short* kr0a = &sKa[lq*512 + kqo];
    const unsigned short* kr1a = &sKa[(16 + lq)*512 + kqo];
    const unsigned short* kr0b = &sKb[lq*64 + kqo];
    const unsigned short* kr1b = &sKb[(16 + lq)*64 + kqo];

    // --- K staging per-lane offsets (3 persistent VGPRs, no division)
    const int kq0 = wv*DTOT_ + (lane ^ wv)*8;        // even p: row r=p*4+wv, r&7=wv
    const int kq1 = wv*DTOT_ + (lane ^ (wv + 4))*8;  // odd  p: r&7=wv+4
    const int kob = (t >> 3)*DTOT_ + RANK_ + ((t & 7) ^ ((t >> 3) & 7))*8;

    // V staging coords: row r = p*64 + wv*16 + (lane>>2); physical col
    // (lane&3) stores logical k-granule (lane&3)^((r>>1)&3) -> 2-way reads.
    const int vrow  = wv*16 + (lane >> 2);                       // + p*64
    const int vgcol = (((lane & 3) ^ ((lane >> 3) & 3))) * 8;    // swizzled source
    const int pvsw  = (quad ^ ((lq >> 1) & 3)) * 8;              // PV read group

#define ISSUE_K(TPTR)                                                          \
    _Pragma("unroll")                                                          \
    for (int p = 0; p < 8; ++p)                                                \
        async_copy16((TPTR) + (p*4)*DTOT_ + ((p & 1) ? kq1 : kq0),             \
                     &sKa[p*2048 + wv*512]);                                   \
    async_copy16((TPTR) + kob, &sKb[wv*512])

    const unsigned short* ktp = kcb;      // K tile pointer, +32*DTOT_ per tile
    ISSUE_K(ktp);
    ktp += 32 * DTOT_;

    for (int tt = 0; tt < ntiles; ++tt) {
        const int k0 = tt << 5;
        // opaque Q pointers: defeat LICM so the 36 Q loads below cannot be
        // hoisted out of the tile loop into persistent registers (v9 spill).
        const unsigned short* q0s = qrow;
        const unsigned short* q1s = qrow + (size_t)64 * DTOT_;
        asm volatile("" : "+v"(q0s), "+v"(q1s));

        __syncthreads();   // barrier1: K(tt) DMA drained -> sK valid; sVW free
        {   // VW stage: 2 DMAs, hidden behind QK+softmax
#pragma unroll
            for (int p = 0; p < 2; ++p) {
                const unsigned short* vsrc =
                    vtb + (size_t)(p*64 + vrow) * S_ + k0 + vgcol;
                async_copy16(vsrc, &sVW[p*2048 + wv*512]);
            }
        }
        // QK^T: each K-frag LDS read feeds both q-groups (Q streamed from L2)
        f32x4 s0a = {0.f,0.f,0.f,0.f}, s0b = {0.f,0.f,0.f,0.f};
        f32x4 s1a = {0.f,0.f,0.f,0.f}, s1b = {0.f,0.f,0.f,0.f};
        f32x4 u0a = {0.f,0.f,0.f,0.f}, u0b = {0.f,0.f,0.f,0.f};
        f32x4 u1a = {0.f,0.f,0.f,0.f}, u1b = {0.f,0.f,0.f,0.f};
#pragma unroll
        for (int c = 0; c < 16; c += 2) {
            short8 ka0 = *(const short8*)(kr0a + c*32 + selA);
            short8 kb0 = *(const short8*)(kr0a + c*32 + selB);
            short8 ka1 = *(const short8*)(kr1a + c*32 + selA);
            short8 kb1 = *(const short8*)(kr1a + c*32 + selB);
            short8 g0a = *(const short8*)(q0s + c*32);
            short8 g0b = *(const short8*)(q0s + (c+1)*32);
            short8 g1a = *(const short8*)(q1s + c*32);
            short8 g1b = *(const short8*)(q1s + (c+1)*32);
            s0a = __builtin_amdgcn_mfma_f32_16x16x32_bf16(ka0, g0a, s0a, 0, 0, 0);
            s1a = __builtin_amdgcn_mfma_f32_16x16x32_bf16(ka1, g0a, s1a, 0, 0, 0);
            s0b = __builtin_amdgcn_mfma_f32_16x16x32_bf16(kb0, g0b, s0b, 0, 0, 0);
            s1b = __builtin_amdgcn_mfma_f32_16x16x32_bf16(kb1, g0b, s1b, 0, 0, 0);
            u0a = __builtin_amdgcn_mfma_f32_16x16x32_bf16(ka0, g1a, u0a, 0, 0, 0);
            u1a = __builtin_amdgcn_mfma_f32_16x16x32_bf16(ka1, g1a, u1a, 0, 0, 0);
            u0b = __builtin_amdgcn_mfma_f32_16x16x32_bf16(kb0, g1b, u0b, 0, 0, 0);
            u1b = __builtin_amdgcn_mfma_f32_16x16x32_bf16(kb1, g1b, u1b, 0, 0, 0);
        }
        {   // RoPE chunks (c = 16,17) from sKb
            short8 ka0 = *(const short8*)(kr0b + selA);
            short8 kb0 = *(const short8*)(kr0b + selB);
            short8 ka1 = *(const short8*)(kr1b + selA);
            short8 kb1 = *(const short8*)(kr1b + selB);
            short8 g0a = *(const short8*)(q0s + 16*32);
            short8 g0b = *(const short8*)(q0s + 17*32);
            short8 g1a = *(const short8*)(q1s + 16*32);
            short8 g1b = *(const short8*)(q1s + 17*32);
            s0a = __builtin_amdgcn_mfma_f32_16x16x32_bf16(ka0, g0a, s0a, 0, 0, 0);
            s1a = __builtin_amdgcn_mfma_f32_16x16x32_bf16(ka1, g0a, s1a, 0, 0, 0);
            s0b = __builtin_amdgcn_mfma_f32_16x16x32_bf16(kb0, g0b, s0b, 0, 0, 0);
            s1b = __builtin_amdgcn_mfma_f32_16x16x32_bf16(kb1, g0b, s1b, 0, 0, 0);
            u0a = __builtin_amdgcn_mfma_f32_16x16x32_bf16(ka0, g1a, u0a, 0, 0, 0);
            u1a = __builtin_amdgcn_mfma_f32_16x16x32_bf16(ka1, g1a, u1a, 0, 0, 0);
            u0b = __builtin_amdgcn_mfma_f32_16x16x32_bf16(kb0, g1b, u0b, 0, 0, 0);
            u1b = __builtin_amdgcn_mfma_f32_16x16x32_bf16(kb1, g1b, u1b, 0, 0, 0);
        }
        // online softmax per group (T13 defer-max THR=8)
        float sv0[8], sv1[8];
#pragma unroll
        for (int r = 0; r < 4; ++r) {
            int kk0 = k0 + quad*4 + r;
            sv0[r]     = (kk0      <= myq0)      ? (s0a[r] + s0b[r]) * scale : -1e30f;
            sv0[r + 4] = (kk0 + 16 <= myq0)      ? (s1a[r] + s1b[r]) * scale : -1e30f;
            sv1[r]     = (kk0      <= myq0 + 64) ? (u0a[r] + u0b[r]) * scale : -1e30f;
            sv1[r + 4] = (kk0 + 16 <= myq0 + 64) ? (u1a[r] + u1b[r]) * scale : -1e30f;
        }
        float mx0 = sv0[0], mx1 = sv1[0];
#pragma unroll
        for (int i = 1; i < 8; ++i) { mx0 = fmaxf(mx0, sv0[i]); mx1 = fmaxf(mx1, sv1[i]); }
        mx0 = fmaxf(mx0, __shfl_xor(mx0, 16));
        mx0 = fmaxf(mx0, __shfl_xor(mx0, 32));
        mx1 = fmaxf(mx1, __shfl_xor(mx1, 16));
        mx1 = fmaxf(mx1, __shfl_xor(mx1, 32));
        if (!__all(mx0 <= mi0 + 8.f)) {
            const float m_new = fmaxf(mi0, mx0);
            const float alpha = __expf(mi0 - m_new);
            mi0 = m_new; li0 *= alpha;
#pragma unroll
            for (int i = 0; i < 8; ++i) {
                o0[i][0]*=alpha; o0[i][1]*=alpha; o0[i][2]*=alpha; o0[i][3]*=alpha;
            }
        }
        if (!__all(mx1 <= mi1 + 8.f)) {
            const float m_new = fmaxf(mi1, mx1);
            const float alpha = __expf(mi1 - m_new);
            mi1 = m_new; li1 *= alpha;
#pragma unroll
            for (int i = 0; i < 8; ++i) {
                o1[i][0]*=alpha; o1[i][1]*=alpha; o1[i][2]*=alpha; o1[i][3]*=alpha;
            }
        }
        float p0[8], p1[8]; float ls0 = 0.f, ls1 = 0.f;
#pragma unroll
        for (int i = 0; i < 8; ++i) {
            p0[i] = __expf(sv0[i] - mi0); ls0 += p0[i];
            p1[i] = __expf(sv1[i] - mi1); ls1 += p1[i];
        }
        ls0 += __shfl_xor(ls0, 16); ls0 += __shfl_xor(ls0, 32); li0 += ls0;
        ls1 += __shfl_xor(ls1, 16); ls1 += __shfl_xor(ls1, 32); li1 += ls1;
        short8 pb0 = quad_transpose(pack2bf(p0[0], p0[1]), pack2bf(p0[2], p0[3]),
                                    pack2bf(p0[4], p0[5]), pack2bf(p0[6], p0[7]),
                                    srcA, srcB, lowq);
        short8 pb1 = quad_transpose(pack2bf(p1[0], p1[1]), pack2bf(p1[2], p1[3]),
                                    pack2bf(p1[4], p1[5]), pack2bf(p1[6], p1[7]),
                                    srcA, srcB, lowq);
        __syncthreads();   // barrier2: VW(tt) DMA drained; all QK reads of sK done
        // K(t+1) DMA: issued now, hidden under PV, drained at next barrier1
        if (tt + 1 < ntiles) {
            ISSUE_K(ktp);
            ktp += 32 * DTOT_;
        }
        // PV: each VW read feeds both groups
#pragma unroll
        for (int dt = 0; dt < 8; ++dt) {
            short8 va = *(const short8*)&sVW[(dt*16 + lq)*32 + pvsw];
            o0[dt] = __builtin_amdgcn_mfma_f32_16x16x32_bf16(va, pb0, o0[dt], 0, 0, 0);
            o1[dt] = __builtin_amdgcn_mfma_f32_16x16x32_bf16(va, pb1, o1[dt], 0, 0, 0);
        }
    }

    // store: transpose o (rows=d, cols=q) -> lane holds q=lq, 8 consecutive d.
    const float inv0 = 1.0f / li0;
    const float inv1 = 1.0f / li1;
    unsigned short* orow =
        attn_bf + ((size_t)b * S_ + q0 + wv*16 + lq) * (NH_*VDIM_) + h*VDIM_;
    unsigned short* orow1 = orow + (size_t)64 * (NH_*VDIM_);
#pragma unroll
    for (int dt2 = 0; dt2 < 4; ++dt2) {
        short8 xa = quad_transpose(
            pack2bf(o0[2*dt2][0]*inv0,   o0[2*dt2][1]*inv0),
            pack2bf(o0[2*dt2][2]*inv0,   o0[2*dt2][3]*inv0),
            pack2bf(o0[2*dt2+1][0]*inv0, o0[2*dt2+1][1]*inv0),
            pack2bf(o0[2*dt2+1][2]*inv0, o0[2*dt2+1][3]*inv0),
            srcA, srcB, lowq);
        *(short8*)(orow + dt2*32 + quad*8) = xa;
        short8 xb = quad_transpose(
            pack2bf(o1[2*dt2][0]*inv1,   o1[2*dt2][1]*inv1),
            pack2bf(o1[2*dt2][2]*inv1,   o1[2*dt2][3]*inv1),
            pack2bf(o1[2*dt2+1][0]*inv1, o1[2*dt2+1][1]*inv1),
            pack2bf(o1[2*dt2+1][2]*inv1, o1[2*dt2+1][3]*inv1),
            srcA, srcB, lowq);
        *(short8*)(orow1 + dt2*32 + quad*8) = xb;
    }
}

extern "C" void kernel_launch(void* const* d_in, const int* in_sizes, int n_in,
                              void* d_out, int out_size, void* d_ws, size_t ws_size,
                              hipStream_t stream)
{
    const float* hidden  = (const float*)d_in[0];
    // d_in[1] = attention_mask (guaranteed causal tril, handled analytically)
    const int*   pos_ids = (const int*)d_in[2];
    const float* cosc    = (const float*)d_in[3];
    const float* sinc    = (const float*)d_in[4];
    const float* Wq      = (const float*)d_in[5];
    const float* Wkv_a   = (const float*)d_in[6];
    const float* lnw     = (const float*)d_in[7];
    const float* Wkv_b   = (const float*)d_in[8];
    const float* Wo      = (const float*)d_in[9];
    float* out = (float*)d_out;

    const int M = B_ * S_;  // 4096
    char* ws = (char*)d_ws;
    // Workspace layout (139.5 MB total, time-disjoint aliases):
    unsigned short* hidden_bf = (unsigned short*)ws;                 // 16.78 MB (live 1-5)
    unsigned short* vwT       = (unsigned short*)ws;                 // alias 16.78 MB (live 9-12)
    unsigned short* q_bf      = (unsigned short*)(ws + 16777216);    // 25.17 MB (live 3-11)
    unsigned short* attn_bf   = q_bf;                                // alias (live 12-14, after q_bf dead)
    unsigned short* ckv_bf    = (unsigned short*)(ws + 41943040);    // 4.72 MB (live 5-6)
    unsigned short* wqaT      = ckv_bf;                              // alias 2.10 MB (live 10-11)
    unsigned short* q_cat     = (unsigned short*)(ws + 46661632);    // 75.50 MB (live 7-12)
    unsigned short* k_cat     = (unsigned short*)(ws + 122159104);   // 4.72 MB (live 6-12)
    unsigned short* wT        = (unsigned short*)(ws + 126877696);   // 12.58 MB (WqT/WkvaT/WoT)
    unsigned short* w2bf      = (unsigned short*)(ws + 126877696 + 8388608); // 4.19 MB (live 8-9)

    // 1. hidden -> bf16
    cast_bf16<<<8192, 256, 0, stream>>>(hidden, hidden_bf);
    // 2. WqT = Wq^T bf16 [3072][2048]
    transpose_w<<<dim3(32, 48, 1), 256, 0, stream>>>(Wq, wT, H_, NH_*QHD_, 0, 0);
    // 3. q_bf = hidden @ Wq (bf16 out)
    bgemm2<<<dim3(24, 32, 1), 256, 0, stream>>>(hidden_bf, H_, wT, H_, q_bf, NH_*QHD_, H_, NH_*QHD_, 0);
    // 4. WkvaT bf16 [576][2048]
    transpose_w<<<dim3(32, 9, 1), 256, 0, stream>>>(Wkv_a, wT, H_, DTOT_, 0, 0);
    // 5. ckv_bf = hidden @ Wkv_a (bf16 out, ragged N=576)
    bgemm2<<<dim3(5, 32, 1), 256, 0, stream>>>(hidden_bf, H_, wT, H_, ckv_bf, DTOT_, H_, DTOT_, 0);
    // 6. RMSNorm + k_pe RoPE -> k_cat
    postkv<<<M, 128, 0, stream>>>(ckv_bf, lnw, pos_ids, cosc, sinc, k_cat);
    // 7. q_pe RoPE -> q_cat[...,512:576]
    ropeq<<<M, 512, 0, stream>>>(q_bf, pos_ids, cosc, sinc, q_cat);
    // 8. Wkv_b -> bf16
    wcast<<<(NH_*256*RANK_)/1024, 256, 0, stream>>>(Wkv_b, w2bf);
    // 9. vwT[b,h] = out_absorb[h] @ k_cat[b][:, :512]^T  (bf16, [128][2048] per z)
    bgemm2<<<dim3(16, 1, 32), 256, 0, stream>>>(w2bf, RANK_, k_cat, DTOT_, vwT, S_, RANK_, S_, 2);
    // 10. wqaT[h] = (Wkv_b[h][0:128])^T bf16 [512][128]
    transpose_w<<<dim3(2, 8, 16), 256, 0, stream>>>(Wkv_b, wqaT, NOPE_, RANK_,
                                                    (size_t)256*RANK_, (size_t)RANK_*NOPE_);
    // 11. q_cat[...,0:512] = q_nope @ q_absorb (batched, K=128)
    bgemm2<<<dim3(4, 16, 32), 256, 0, stream>>>(q_bf, NH_*QHD_, wqaT, NOPE_, q_cat, DTOT_, NOPE_, RANK_, 1);
    // 12. flash attention (absorb-V, 32 q/wave, streamed Q) -> attn_bf (bf16)
    flash_attn4<<<dim3(NH_, S_/128, B_), 256, 0, stream>>>(q_cat, k_cat, vwT, attn_bf);
    // 13. WoT bf16 [2048][2048]
    transpose_w<<<dim3(32, 32, 1), 256, 0, stream>>>(Wo, wT, H_, H_, 0, 0);
    // 14. out = attn @ Wo (f32 out)
    bgemm2f<<<dim3(16, 32, 1), 256, 0, stream>>>(attn_bf, H_, wT, H_, out, H_, H_, H_);
}

// Round 8
// 520.440 us; speedup vs baseline: 1.6484x; 1.6484x over previous
//
#include <hip/hip_runtime.h>
#include <math.h>

#define B_    2
#define S_    2048
#define H_    2048
#define NH_   16
#define NOPE_ 128
#define ROPE_ 64
#define VDIM_ 128
#define RANK_ 512
#define QHD_  192   // NOPE + ROPE
#define DTOT_ 576   // RANK + ROPE

typedef short short8 __attribute__((ext_vector_type(8)));
typedef float f32x4 __attribute__((ext_vector_type(4)));

__device__ __forceinline__ unsigned short f2bf(float f) {
    unsigned u = __float_as_uint(f);
    u += 0x7fffu + ((u >> 16) & 1u);
    return (unsigned short)(u >> 16);
}
__device__ __forceinline__ float bf2f(unsigned short u) {
    return __uint_as_float((unsigned)u << 16);
}
__device__ __forceinline__ unsigned pack2bf(float a, float b) {
    return (unsigned)f2bf(a) | ((unsigned)f2bf(b) << 16);
}
__device__ __forceinline__ unsigned long long pack4bf(float a, float b, float c, float d) {
    return (unsigned long long)pack2bf(a, b) | ((unsigned long long)pack2bf(c, d) << 32);
}
union i4s8 { int4 i; short8 s; };

// Async global->LDS, 16B per lane. LDS dest = wave-uniform base + lane*16.
typedef __attribute__((address_space(3))) unsigned int lds_u32_t;
typedef __attribute__((address_space(1))) const unsigned int glob_u32_t;
__device__ __forceinline__ void async_copy16(const unsigned short* g, unsigned short* l) {
    __builtin_amdgcn_global_load_lds((glob_u32_t*)g, (lds_u32_t*)l, 16, 0, 0);
}

// ---------------------------------------------------------------------------
// cast fp32 -> bf16, 4 elems/thread.
// ---------------------------------------------------------------------------
__global__ __launch_bounds__(256) void cast_bf16(const float* __restrict__ in,
                                                 unsigned short* __restrict__ out)
{
    const size_t i = ((size_t)blockIdx.x * 256 + threadIdx.x) * 4;
    float4 v = *(const float4*)(in + i);
    *(unsigned long long*)(out + i) = pack4bf(v.x, v.y, v.z, v.w);
}

// ---------------------------------------------------------------------------
// Transpose + cast: in fp32 [Rr][Cc] (batched) -> out bf16 [Cc][Rr].
// grid (Rr/64, Cc/64, batch), 256 threads.
// ---------------------------------------------------------------------------
__global__ __launch_bounds__(256) void transpose_w(const float* __restrict__ in,
                                                   unsigned short* __restrict__ out,
                                                   int Rr, int Cc,
                                                   size_t inBatch, size_t outBatch)
{
    __shared__ unsigned short tl[64][72];
    in  += (size_t)blockIdx.z * inBatch;
    out += (size_t)blockIdx.z * outBatch;
    const int t  = threadIdx.x;
    const int r0 = blockIdx.x * 64;
    const int c0 = blockIdx.y * 64;
    const int lr = t >> 4;
    const int lc = (t & 15) * 4;
#pragma unroll
    for (int r = 0; r < 4; ++r) {
        float4 v = *(const float4*)(in + (size_t)(r0 + lr*4 + r) * Cc + c0 + lc);
        tl[lr*4 + r][lc+0] = f2bf(v.x); tl[lr*4 + r][lc+1] = f2bf(v.y);
        tl[lr*4 + r][lc+2] = f2bf(v.z); tl[lr*4 + r][lc+3] = f2bf(v.w);
    }
    __syncthreads();
#pragma unroll
    for (int r = 0; r < 4; ++r) {
        ushort4 v;
        v.x = tl[lc+0][lr*4+r]; v.y = tl[lc+1][lr*4+r];
        v.z = tl[lc+2][lr*4+r]; v.w = tl[lc+3][lr*4+r];
        *(ushort4*)(out + (size_t)(c0 + lr*4 + r) * Rr + r0 + lc) = v;
    }
}

// ---------------------------------------------------------------------------
// bf16 MFMA GEMM, m97-style: C = A[M][K](lda) @ Bt^T, Bt bf16 [N][K](ldb).
// 128x128 tile, 4 waves, BK=32, global_load_lds staging. N-guard for ragged N.
// mode 0: plain (T1 XCD-swizzled tile mapping; nwg%8==0 at all call sites).
// mode 1: batched q-absorb. mode 2: batched VW^T = out_absorb @ k_cat^T.
// ---------------------------------------------------------------------------
#define BGEMM_BODY(STORE_STMT)                                                     \
    __shared__ unsigned short Al[128*32];                                          \
    __shared__ unsigned short Bl[128*32];                                          \
    const int t = threadIdx.x;                                                     \
    const int wv = t >> 6;                                                         \
    const int lane = t & 63;                                                       \
    const int lq = lane & 15, quad = lane >> 4;                                    \
    const int m0 = by * 128, n0 = bx * 128;                                        \
    const int wrow = (wv >> 1) * 64, wcol = (wv & 1) * 64;                         \
    const int srow = lane >> 2;                                                    \
    const int scol = (lane & 3) * 8;                                               \
    f32x4 acc[4][4] = {};                                                          \
    for (int k0 = 0; k0 < K; k0 += 32) {                                           \
        _Pragma("unroll")                                                          \
        for (int pA = 0; pA < 2; ++pA) {                                           \
            const unsigned short* src =                                            \
                A + (size_t)(m0 + pA*64 + wv*16 + srow) * lda + k0 + scol;         \
            async_copy16(src, &Al[pA*2048 + wv*512]);                              \
        }                                                                          \
        _Pragma("unroll")                                                          \
        for (int pB = 0; pB < 2; ++pB) {                                           \
            int brow = n0 + pB*64 + wv*16 + srow;                                  \
            if (brow > N - 1) brow = N - 1;                                        \
            const unsigned short* src = B + (size_t)brow * ldb + k0 + scol;        \
            async_copy16(src, &Bl[pB*2048 + wv*512]);                              \
        }                                                                          \
        __syncthreads();                                                           \
        short8 af[4], bf[4];                                                       \
        _Pragma("unroll")                                                          \
        for (int i = 0; i < 4; ++i) {                                              \
            af[i] = *(const short8*)&Al[(wrow + i*16 + lq)*32 + quad*8];           \
            bf[i] = *(const short8*)&Bl[(wcol + i*16 + lq)*32 + quad*8];           \
        }                                                                          \
        _Pragma("unroll")                                                          \
        for (int mi = 0; mi < 4; ++mi)                                             \
            _Pragma("unroll")                                                      \
            for (int ni = 0; ni < 4; ++ni)                                         \
                acc[mi][ni] = __builtin_amdgcn_mfma_f32_16x16x32_bf16(             \
                    af[mi], bf[ni], acc[mi][ni], 0, 0, 0);                         \
        __syncthreads();                                                           \
    }                                                                              \
    _Pragma("unroll")                                                              \
    for (int mi = 0; mi < 4; ++mi)                                                 \
        _Pragma("unroll")                                                          \
        for (int ni = 0; ni < 4; ++ni) {                                           \
            int col = n0 + wcol + ni*16 + lq;                                      \
            if (col < N) {                                                         \
                _Pragma("unroll")                                                  \
                for (int r = 0; r < 4; ++r)                                        \
                    STORE_STMT;                                                    \
            }                                                                      \
        }

// T1 bijective XCD swizzle (requires nwg % 8 == 0).
#define XCD_SWZ(BX, BY)                                                            \
    {                                                                              \
        const int nx = gridDim.x;                                                  \
        const int nwg = nx * gridDim.y;                                            \
        const int wg = BY * nx + BX;                                               \
        const int nw = (wg & 7) * (nwg >> 3) + (wg >> 3);                          \
        BX = nw % nx; BY = nw / nx;                                                \
    }

__global__ __launch_bounds__(256, 2) void bgemm2(const unsigned short* __restrict__ A,
                                                 int lda,
                                                 const unsigned short* __restrict__ B,
                                                 int ldb,
                                                 unsigned short* __restrict__ C,
                                                 int ldc, int K, int N, int qcmode)
{
    int bx = blockIdx.x, by = blockIdx.y;
    if (qcmode == 1) {
        const int z = blockIdx.z;
        A += (size_t)(z >> 4) * S_ * (NH_*QHD_) + (z & 15) * QHD_;
        B += (size_t)(z & 15) * RANK_ * NOPE_;
        C += (size_t)z * S_ * DTOT_;
    } else if (qcmode == 2) {
        // VW^T[b,h] [128][2048] = out_absorb[h] [128][512] @ (k_cat[b][:, :512])^T
        const int z = blockIdx.z;
        A += (size_t)(z & 15) * 256 * RANK_ + (size_t)NOPE_ * RANK_;
        B += (size_t)(z >> 4) * S_ * DTOT_;
        C += (size_t)z * VDIM_ * S_;
    } else {
        XCD_SWZ(bx, by);
    }
    BGEMM_BODY(C[(size_t)(m0 + wrow + mi*16 + quad*4 + r) * ldc + col] = f2bf(acc[mi][ni][r]))
}

__global__ __launch_bounds__(256, 2) void bgemm2f(const unsigned short* __restrict__ A,
                                                  int lda,
                                                  const unsigned short* __restrict__ B,
                                                  int ldb,
                                                  float* __restrict__ C,
                                                  int ldc, int K, int N)
{
    int bx = blockIdx.x, by = blockIdx.y;
    XCD_SWZ(bx, by);
    BGEMM_BODY(C[(size_t)(m0 + wrow + mi*16 + quad*4 + r) * ldc + col] = acc[mi][ni][r])
}

// ---------------------------------------------------------------------------
// Per (b,s) row: RMSNorm ckv (bf16 in) -> k_cat[0:512]; RoPE k_pe -> [512:576].
// ---------------------------------------------------------------------------
__global__ __launch_bounds__(128) void postkv(const unsigned short* __restrict__ ckv_bf,
                                              const float* __restrict__ lnw,
                                              const int*   __restrict__ pos_ids,
                                              const float* __restrict__ cosc,
                                              const float* __restrict__ sinc,
                                              unsigned short* __restrict__ k_cat)
{
    const int row = blockIdx.x;
    const int t   = threadIdx.x;
    const unsigned short* src = ckv_bf + (size_t)row * DTOT_;
    __shared__ float red[128];

    ushort4 v = *(const ushort4*)(src + t * 4);
    float x0 = bf2f(v.x), x1 = bf2f(v.y), x2 = bf2f(v.z), x3 = bf2f(v.w);
    red[t] = x0*x0 + x1*x1 + x2*x2 + x3*x3;
    __syncthreads();
    for (int off = 64; off > 0; off >>= 1) {
        if (t < off) red[t] += red[t + off];
        __syncthreads();
    }
    const float rs = rsqrtf(red[0] / (float)RANK_ + 1e-6f);

    unsigned short* kc = k_cat + (size_t)row * DTOT_;
    *(unsigned long long*)(kc + t*4) =
        pack4bf(x0*rs*lnw[t*4+0], x1*rs*lnw[t*4+1], x2*rs*lnw[t*4+2], x3*rs*lnw[t*4+3]);

    if (t < 32) {
        const int pos = pos_ids[row];
        const float c  = cosc[pos * ROPE_ + t];
        const float sn = sinc[pos * ROPE_ + t];
        const float y0 = bf2f(src[RANK_ + 2*t]);
        const float y1 = bf2f(src[RANK_ + 2*t + 1]);
        kc[RANK_ + t]      = f2bf(y0*c - y1*sn);
        kc[RANK_ + 32 + t] = f2bf(y1*c + y0*sn);
    }
}

// ---------------------------------------------------------------------------
// RoPE q_pe (bf16 in) -> q_cat[...,512:576]. grid = B*S, 512 threads.
// ---------------------------------------------------------------------------
__global__ __launch_bounds__(512) void ropeq(const unsigned short* __restrict__ q_bf,
                                             const int*   __restrict__ pos_ids,
                                             const float* __restrict__ cosc,
                                             const float* __restrict__ sinc,
                                             unsigned short* __restrict__ q_cat)
{
    const int row = blockIdx.x;
    const int t   = threadIdx.x;
    const int h   = t >> 5;
    const int i   = t & 31;
    const int pos = pos_ids[row];
    const float c  = cosc[pos * ROPE_ + i];
    const float sn = sinc[pos * ROPE_ + i];
    const unsigned short* qrow = q_bf + (size_t)row * (NH_*QHD_) + h * QHD_ + NOPE_;
    const float x0 = bf2f(qrow[2*i]);
    const float x1 = bf2f(qrow[2*i + 1]);
    const int b = row >> 11, s = row & 2047;
    unsigned short* qc = q_cat + ((size_t)(b * NH_ + h) * S_ + s) * DTOT_ + RANK_;
    qc[i]      = f2bf(x0*c - x1*sn);
    qc[32 + i] = f2bf(x1*c + x0*sn);
}

__global__ __launch_bounds__(256) void wcast(const float* __restrict__ w,
                                             unsigned short* __restrict__ wbf)
{
    const size_t i = ((size_t)blockIdx.x * 256 + threadIdx.x) * 4;
    float4 v = *(const float4*)(w + i);
    *(unsigned long long*)(wbf + i) = pack4bf(v.x, v.y, v.z, v.w);
}

// ---------------------------------------------------------------------------
// Flash attention v11 = v8 (proven 174us: absorb-V, 16 q-rows/wave, K+V DMA
// pipelined) + T5 s_setprio around the QK and PV MFMA clusters. v9/v10's
// 32 q/wave line is abandoned: the needed 144 persistent Q VGPRs spill at
// 2 waves/SIMD (v9: WRITE 700MB) and L2-streaming thrashes (v10: co-resident
// working set 9.4MB/XCD > 4MB L2 -> FETCH 1.2GB from HBM).
// ---------------------------------------------------------------------------
__device__ __forceinline__ short8 quad_transpose(unsigned d0, unsigned d1,
                                                 unsigned d2, unsigned d3,
                                                 int srcA, int srcB, bool lowquad)
{
    int e0 = __shfl((int)d0, srcA, 64);
    int e1 = __shfl((int)d1, srcA, 64);
    int e2 = __shfl((int)d2, srcA, 64);
    int e3 = __shfl((int)d3, srcA, 64);
    int f0 = __shfl((int)d0, srcB, 64);
    int f1 = __shfl((int)d1, srcB, 64);
    int f2 = __shfl((int)d2, srcB, 64);
    int f3 = __shfl((int)d3, srcB, 64);
    i4s8 u;
    u.i.x = lowquad ? e0 : e2;
    u.i.y = lowquad ? e1 : e3;
    u.i.z = lowquad ? f0 : f2;
    u.i.w = lowquad ? f1 : f3;
    return u.s;
}

__global__ __launch_bounds__(256, 2) void flash_attn4(
    const unsigned short* __restrict__ q_cat,
    const unsigned short* __restrict__ k_cat,
    const unsigned short* __restrict__ vwt,
    unsigned short* __restrict__ attn_bf)
{
    __shared__ unsigned short sKa[32*512];   // 32768 B, RANK part, swizzled
    __shared__ unsigned short sKb[32*64];    //  4096 B, RoPE part, swizzled
    __shared__ unsigned short sVW[128*32];   //  8192 B, VW^T tile, swizzled

    const int t    = threadIdx.x;
    const int wv   = t >> 6;
    const int lane = t & 63;
    const int lq   = lane & 15;
    const int quad = lane >> 4;
    const int h    = blockIdx.x;
    const int q0   = (31 - blockIdx.y) * 64;   // longest strips first
    const int b    = blockIdx.z;
    const int srcA = lq + ((quad & 1) << 5);
    const int srcB = srcA + 16;
    const bool lowq = quad < 2;
    const int myq  = q0 + wv*16 + lq;

    // Q fragments (loop-invariant)
    const unsigned short* qrow =
        q_cat + (((size_t)(b*NH_ + h)) * S_ + q0 + wv*16 + lq) * DTOT_ + quad*8;
    short8 qf[18];
#pragma unroll
    for (int c = 0; c < 18; ++c) qf[c] = *(const short8*)(qrow + c*32);

    const unsigned short* kcb = k_cat + (size_t)b * S_ * DTOT_;
    const unsigned short* vtb = vwt + (size_t)(b*NH_ + h) * VDIM_ * S_;

    f32x4 o[8];
#pragma unroll
    for (int i = 0; i < 8; ++i) o[i] = (f32x4){0.f, 0.f, 0.f, 0.f};
    float m_i = -1e30f, l_i = 0.f;
    const float scale = 0.0721687836f;  // 1/sqrt(192)
    const int ntiles = (q0 >> 5) + 2;

    // --- K read-side swizzle: logical granule (row, g) lives at physical
    // g^(row&7); rows lq and 16+lq share (lq&7).
    const int swz  = lq & 7;
    const int selA = (swz >> 2) * 32;           // shorts: +32 if bit2 of swz
    const int selB = 32 - selA;
    const int kqo  = (quad ^ (swz & 3)) * 8;    // shorts within 128B block
    const unsigned short* kr0a = &sKa[lq*512 + kqo];
    const unsigned short* kr1a = &sKa[(16 + lq)*512 + kqo];
    const unsigned short* kr0b = &sKb[lq*64 + kqo];
    const unsigned short* kr1b = &sKb[(16 + lq)*64 + kqo];

    // --- K staging per-lane offsets (3 persistent VGPRs, no division)
    const int kq0 = wv*DTOT_ + (lane ^ wv)*8;        // even p: row r=p*4+wv, r&7=wv
    const int kq1 = wv*DTOT_ + (lane ^ (wv + 4))*8;  // odd  p: r&7=wv+4
    const int kob = (t >> 3)*DTOT_ + RANK_ + ((t & 7) ^ ((t >> 3) & 7))*8;

    // V staging coords: row r = p*64 + wv*16 + (lane>>2); physical col
    // (lane&3) stores logical k-granule (lane&3)^((r>>1)&3) -> 2-way reads.
    const int vrow  = wv*16 + (lane >> 2);                       // + p*64
    const int vgcol = (((lane & 3) ^ ((lane >> 3) & 3))) * 8;    // swizzled source
    const int pvsw  = (quad ^ ((lq >> 1) & 3)) * 8;              // PV read group

#define ISSUE_K(TPTR)                                                          \
    _Pragma("unroll")                                                          \
    for (int p = 0; p < 8; ++p)                                                \
        async_copy16((TPTR) + (p*4)*DTOT_ + ((p & 1) ? kq1 : kq0),             \
                     &sKa[p*2048 + wv*512]);                                   \
    async_copy16((TPTR) + kob, &sKb[wv*512])

    const unsigned short* ktp = kcb;      // K tile pointer, +32*DTOT_ per tile
    ISSUE_K(ktp);
    ktp += 32 * DTOT_;

    for (int tt = 0; tt < ntiles; ++tt) {
        const int k0 = tt << 5;
        __syncthreads();   // barrier1: K(tt) DMA drained -> sK valid; sVW free
        {   // VW stage: 2 DMAs, hidden behind QK+softmax
#pragma unroll
            for (int p = 0; p < 2; ++p) {
                const unsigned short* vsrc =
                    vtb + (size_t)(p*64 + vrow) * S_ + k0 + vgcol;
                async_copy16(vsrc, &sVW[p*2048 + wv*512]);
            }
        }
        // QK^T (swizzled reads: per-lane base + compile-time offsets)
        f32x4 s0a = {0.f,0.f,0.f,0.f}, s0b = {0.f,0.f,0.f,0.f};
        f32x4 s1a = {0.f,0.f,0.f,0.f}, s1b = {0.f,0.f,0.f,0.f};
        __builtin_amdgcn_s_setprio(1);
#pragma unroll
        for (int c = 0; c < 16; c += 2) {
            short8 ka0 = *(const short8*)(kr0a + c*32 + selA);
            short8 kb0 = *(const short8*)(kr0a + c*32 + selB);
            short8 ka1 = *(const short8*)(kr1a + c*32 + selA);
            short8 kb1 = *(const short8*)(kr1a + c*32 + selB);
            s0a = __builtin_amdgcn_mfma_f32_16x16x32_bf16(ka0, qf[c],   s0a, 0, 0, 0);
            s1a = __builtin_amdgcn_mfma_f32_16x16x32_bf16(ka1, qf[c],   s1a, 0, 0, 0);
            s0b = __builtin_amdgcn_mfma_f32_16x16x32_bf16(kb0, qf[c+1], s0b, 0, 0, 0);
            s1b = __builtin_amdgcn_mfma_f32_16x16x32_bf16(kb1, qf[c+1], s1b, 0, 0, 0);
        }
        {   // RoPE chunks (c = 16,17) from sKb
            short8 ka0 = *(const short8*)(kr0b + selA);
            short8 kb0 = *(const short8*)(kr0b + selB);
            short8 ka1 = *(const short8*)(kr1b + selA);
            short8 kb1 = *(const short8*)(kr1b + selB);
            s0a = __builtin_amdgcn_mfma_f32_16x16x32_bf16(ka0, qf[16], s0a, 0, 0, 0);
            s1a = __builtin_amdgcn_mfma_f32_16x16x32_bf16(ka1, qf[16], s1a, 0, 0, 0);
            s0b = __builtin_amdgcn_mfma_f32_16x16x32_bf16(kb0, qf[17], s0b, 0, 0, 0);
            s1b = __builtin_amdgcn_mfma_f32_16x16x32_bf16(kb1, qf[17], s1b, 0, 0, 0);
        }
        __builtin_amdgcn_s_setprio(0);
        // online softmax (per-lane q-row = myq), T13 defer-max THR=8
        float sv[8];
#pragma unroll
        for (int r = 0; r < 4; ++r) {
            int kk0 = k0 + quad*4 + r;
            sv[r]     = (kk0      <= myq) ? (s0a[r] + s0b[r]) * scale : -1e30f;
            sv[r + 4] = (kk0 + 16 <= myq) ? (s1a[r] + s1b[r]) * scale : -1e30f;
        }
        float mx = sv[0];
#pragma unroll
        for (int i = 1; i < 8; ++i) mx = fmaxf(mx, sv[i]);
        mx = fmaxf(mx, __shfl_xor(mx, 16));
        mx = fmaxf(mx, __shfl_xor(mx, 32));
        if (!__all(mx <= m_i + 8.f)) {     // wave-uniform branch, rare after warmup
            const float m_new = fmaxf(m_i, mx);
            const float alpha = __expf(m_i - m_new);
            m_i = m_new;
            l_i *= alpha;
#pragma unroll
            for (int i = 0; i < 8; ++i) {
                o[i][0]*=alpha; o[i][1]*=alpha; o[i][2]*=alpha; o[i][3]*=alpha;
            }
        }
        float p[8]; float ls = 0.f;
#pragma unroll
        for (int i = 0; i < 8; ++i) { p[i] = __expf(sv[i] - m_i); ls += p[i]; }
        ls += __shfl_xor(ls, 16);
        ls += __shfl_xor(ls, 32);
        l_i += ls;
        short8 pb = quad_transpose(pack2bf(p[0], p[1]), pack2bf(p[2], p[3]),
                                   pack2bf(p[4], p[5]), pack2bf(p[6], p[7]),
                                   srcA, srcB, lowq);
        __syncthreads();   // barrier2: VW(tt) DMA drained; all QK reads of sK done
        // K(t+1) DMA: issued now, hidden under PV, drained at next barrier1
        if (tt + 1 < ntiles) {
            ISSUE_K(ktp);
            ktp += 32 * DTOT_;
        }
        // PV: o[dt] covers d = dt*16 + quad*4 + r for q-col = myq
        __builtin_amdgcn_s_setprio(1);
#pragma unroll
        for (int dt = 0; dt < 8; ++dt) {
            short8 va = *(const short8*)&sVW[(dt*16 + lq)*32 + pvsw];
            o[dt] = __builtin_amdgcn_mfma_f32_16x16x32_bf16(va, pb, o[dt], 0, 0, 0);
        }
        __builtin_amdgcn_s_setprio(0);
    }

    // store: transpose o (rows=d, cols=q) -> lane holds q=lq, 8 consecutive d.
    const float inv = 1.0f / l_i;
    unsigned short* orow =
        attn_bf + ((size_t)b * S_ + q0 + wv*16 + lq) * (NH_*VDIM_) + h*VDIM_;
#pragma unroll
    for (int dt2 = 0; dt2 < 4; ++dt2) {
        short8 xa = quad_transpose(
            pack2bf(o[2*dt2][0]*inv,   o[2*dt2][1]*inv),
            pack2bf(o[2*dt2][2]*inv,   o[2*dt2][3]*inv),
            pack2bf(o[2*dt2+1][0]*inv, o[2*dt2+1][1]*inv),
            pack2bf(o[2*dt2+1][2]*inv, o[2*dt2+1][3]*inv),
            srcA, srcB, lowq);
        *(short8*)(orow + dt2*32 + quad*8) = xa;
    }
}

extern "C" void kernel_launch(void* const* d_in, const int* in_sizes, int n_in,
                              void* d_out, int out_size, void* d_ws, size_t ws_size,
                              hipStream_t stream)
{
    const float* hidden  = (const float*)d_in[0];
    // d_in[1] = attention_mask (guaranteed causal tril, handled analytically)
    const int*   pos_ids = (const int*)d_in[2];
    const float* cosc    = (const float*)d_in[3];
    const float* sinc    = (const float*)d_in[4];
    const float* Wq      = (const float*)d_in[5];
    const float* Wkv_a   = (const float*)d_in[6];
    const float* lnw     = (const float*)d_in[7];
    const float* Wkv_b   = (const float*)d_in[8];
    const float* Wo      = (const float*)d_in[9];
    float* out = (float*)d_out;

    const int M = B_ * S_;  // 4096
    char* ws = (char*)d_ws;
    // Workspace layout (139.5 MB total, time-disjoint aliases):
    unsigned short* hidden_bf = (unsigned short*)ws;                 // 16.78 MB (live 1-5)
    unsigned short* vwT       = (unsigned short*)ws;                 // alias 16.78 MB (live 9-12)
    unsigned short* q_bf      = (unsigned short*)(ws + 16777216);    // 25.17 MB (live 3-11)
    unsigned short* attn_bf   = q_bf;                                // alias (live 12-14, after q_bf dead)
    unsigned short* ckv_bf    = (unsigned short*)(ws + 41943040);    // 4.72 MB (live 5-6)
    unsigned short* wqaT      = ckv_bf;                              // alias 2.10 MB (live 10-11)
    unsigned short* q_cat     = (unsigned short*)(ws + 46661632);    // 75.50 MB (live 7-12)
    unsigned short* k_cat     = (unsigned short*)(ws + 122159104);   // 4.72 MB (live 6-12)
    unsigned short* wT        = (unsigned short*)(ws + 126877696);   // 12.58 MB (WqT/WkvaT/WoT)
    unsigned short* w2bf      = (unsigned short*)(ws + 126877696 + 8388608); // 4.19 MB (live 8-9)

    // 1. hidden -> bf16
    cast_bf16<<<8192, 256, 0, stream>>>(hidden, hidden_bf);
    // 2. WqT = Wq^T bf16 [3072][2048]
    transpose_w<<<dim3(32, 48, 1), 256, 0, stream>>>(Wq, wT, H_, NH_*QHD_, 0, 0);
    // 3. q_bf = hidden @ Wq (bf16 out)
    bgemm2<<<dim3(24, 32, 1), 256, 0, stream>>>(hidden_bf, H_, wT, H_, q_bf, NH_*QHD_, H_, NH_*QHD_, 0);
    // 4. WkvaT bf16 [576][2048]
    transpose_w<<<dim3(32, 9, 1), 256, 0, stream>>>(Wkv_a, wT, H_, DTOT_, 0, 0);
    // 5. ckv_bf = hidden @ Wkv_a (bf16 out, ragged N=576)
    bgemm2<<<dim3(5, 32, 1), 256, 0, stream>>>(hidden_bf, H_, wT, H_, ckv_bf, DTOT_, H_, DTOT_, 0);
    // 6. RMSNorm + k_pe RoPE -> k_cat
    postkv<<<M, 128, 0, stream>>>(ckv_bf, lnw, pos_ids, cosc, sinc, k_cat);
    // 7. q_pe RoPE -> q_cat[...,512:576]
    ropeq<<<M, 512, 0, stream>>>(q_bf, pos_ids, cosc, sinc, q_cat);
    // 8. Wkv_b -> bf16
    wcast<<<(NH_*256*RANK_)/1024, 256, 0, stream>>>(Wkv_b, w2bf);
    // 9. vwT[b,h] = out_absorb[h] @ k_cat[b][:, :512]^T  (bf16, [128][2048] per z)
    bgemm2<<<dim3(16, 1, 32), 256, 0, stream>>>(w2bf, RANK_, k_cat, DTOT_, vwT, S_, RANK_, S_, 2);
    // 10. wqaT[h] = (Wkv_b[h][0:128])^T bf16 [512][128]
    transpose_w<<<dim3(2, 8, 16), 256, 0, stream>>>(Wkv_b, wqaT, NOPE_, RANK_,
                                                    (size_t)256*RANK_, (size_t)RANK_*NOPE_);
    // 11. q_cat[...,0:512] = q_nope @ q_absorb (batched, K=128)
    bgemm2<<<dim3(4, 16, 32), 256, 0, stream>>>(q_bf, NH_*QHD_, wqaT, NOPE_, q_cat, DTOT_, NOPE_, RANK_, 1);
    // 12. flash attention (absorb-V) -> attn_bf (bf16)
    flash_attn4<<<dim3(NH_, S_/64, B_), 256, 0, stream>>>(q_cat, k_cat, vwT, attn_bf);
    // 13. WoT bf16 [2048][2048]
    transpose_w<<<dim3(32, 32, 1), 256, 0, stream>>>(Wo, wT, H_, H_, 0, 0);
    // 14. out = attn @ Wo (f32 out)
    bgemm2f<<<dim3(16, 32, 1), 256, 0, stream>>>(attn_bf, H_, wT, H_, out, H_, H_, H_);
}

// Round 9
// 518.939 us; speedup vs baseline: 1.6531x; 1.0029x over previous
//
#include <hip/hip_runtime.h>
#include <math.h>

#define B_    2
#define S_    2048
#define H_    2048
#define NH_   16
#define NOPE_ 128
#define ROPE_ 64
#define VDIM_ 128
#define RANK_ 512
#define QHD_  192   // NOPE + ROPE
#define DTOT_ 576   // RANK + ROPE

typedef short short8 __attribute__((ext_vector_type(8)));
typedef float f32x4 __attribute__((ext_vector_type(4)));

__device__ __forceinline__ unsigned short f2bf(float f) {
    unsigned u = __float_as_uint(f);
    u += 0x7fffu + ((u >> 16) & 1u);
    return (unsigned short)(u >> 16);
}
__device__ __forceinline__ float bf2f(unsigned short u) {
    return __uint_as_float((unsigned)u << 16);
}
__device__ __forceinline__ unsigned pack2bf(float a, float b) {
    return (unsigned)f2bf(a) | ((unsigned)f2bf(b) << 16);
}
__device__ __forceinline__ unsigned long long pack4bf(float a, float b, float c, float d) {
    return (unsigned long long)pack2bf(a, b) | ((unsigned long long)pack2bf(c, d) << 32);
}
union i4s8 { int4 i; short8 s; };

// Async global->LDS, 16B per lane. LDS dest = wave-uniform base + lane*16.
typedef __attribute__((address_space(3))) unsigned int lds_u32_t;
typedef __attribute__((address_space(1))) const unsigned int glob_u32_t;
__device__ __forceinline__ void async_copy16(const unsigned short* g, unsigned short* l) {
    __builtin_amdgcn_global_load_lds((glob_u32_t*)g, (lds_u32_t*)l, 16, 0, 0);
}

// ---------------------------------------------------------------------------
// cast fp32 -> bf16, 4 elems/thread.
// ---------------------------------------------------------------------------
__global__ __launch_bounds__(256) void cast_bf16(const float* __restrict__ in,
                                                 unsigned short* __restrict__ out)
{
    const size_t i = ((size_t)blockIdx.x * 256 + threadIdx.x) * 4;
    float4 v = *(const float4*)(in + i);
    *(unsigned long long*)(out + i) = pack4bf(v.x, v.y, v.z, v.w);
}

// ---------------------------------------------------------------------------
// Transpose + cast: in fp32 [Rr][Cc] (batched) -> out bf16 [Cc][Rr].
// grid (Rr/64, Cc/64, batch), 256 threads.
// ---------------------------------------------------------------------------
__global__ __launch_bounds__(256) void transpose_w(const float* __restrict__ in,
                                                   unsigned short* __restrict__ out,
                                                   int Rr, int Cc,
                                                   size_t inBatch, size_t outBatch)
{
    __shared__ unsigned short tl[64][72];
    in  += (size_t)blockIdx.z * inBatch;
    out += (size_t)blockIdx.z * outBatch;
    const int t  = threadIdx.x;
    const int r0 = blockIdx.x * 64;
    const int c0 = blockIdx.y * 64;
    const int lr = t >> 4;
    const int lc = (t & 15) * 4;
#pragma unroll
    for (int r = 0; r < 4; ++r) {
        float4 v = *(const float4*)(in + (size_t)(r0 + lr*4 + r) * Cc + c0 + lc);
        tl[lr*4 + r][lc+0] = f2bf(v.x); tl[lr*4 + r][lc+1] = f2bf(v.y);
        tl[lr*4 + r][lc+2] = f2bf(v.z); tl[lr*4 + r][lc+3] = f2bf(v.w);
    }
    __syncthreads();
#pragma unroll
    for (int r = 0; r < 4; ++r) {
        ushort4 v;
        v.x = tl[lc+0][lr*4+r]; v.y = tl[lc+1][lr*4+r];
        v.z = tl[lc+2][lr*4+r]; v.w = tl[lc+3][lr*4+r];
        *(ushort4*)(out + (size_t)(c0 + lr*4 + r) * Rr + r0 + lc) = v;
    }
}

// T1 bijective XCD swizzle (requires nwg % 8 == 0).
#define XCD_SWZ(BX, BY)                                                            \
    {                                                                              \
        const int nx = gridDim.x;                                                  \
        const int nwg = nx * gridDim.y;                                            \
        const int wg = BY * nx + BX;                                               \
        const int nw = (wg & 7) * (nwg >> 3) + (wg >> 3);                          \
        BX = nw % nx; BY = nw / nx;                                                \
    }

// ---------------------------------------------------------------------------
// bf16 MFMA GEMM, m97-style: C = A[M][K](lda) @ Bt^T, Bt bf16 [N][K](ldb).
// 128x128 tile, 4 waves, BK=32, global_load_lds staging. N-guard for ragged N.
// mode 0: plain (XCD swizzle). mode 1: batched q-absorb. mode 2: batched VW^T.
// ---------------------------------------------------------------------------
#define BGEMM_BODY(STORE_STMT)                                                     \
    __shared__ unsigned short Al[128*32];                                          \
    __shared__ unsigned short Bl[128*32];                                          \
    const int t = threadIdx.x;                                                     \
    const int wv = t >> 6;                                                         \
    const int lane = t & 63;                                                       \
    const int lq = lane & 15, quad = lane >> 4;                                    \
    const int m0 = by * 128, n0 = bx * 128;                                        \
    const int wrow = (wv >> 1) * 64, wcol = (wv & 1) * 64;                         \
    const int srow = lane >> 2;                                                    \
    const int scol = (lane & 3) * 8;                                               \
    f32x4 acc[4][4] = {};                                                          \
    for (int k0 = 0; k0 < K; k0 += 32) {                                           \
        _Pragma("unroll")                                                          \
        for (int pA = 0; pA < 2; ++pA) {                                           \
            const unsigned short* src =                                            \
                A + (size_t)(m0 + pA*64 + wv*16 + srow) * lda + k0 + scol;         \
            async_copy16(src, &Al[pA*2048 + wv*512]);                              \
        }                                                                          \
        _Pragma("unroll")                                                          \
        for (int pB = 0; pB < 2; ++pB) {                                           \
            int brow = n0 + pB*64 + wv*16 + srow;                                  \
            if (brow > N - 1) brow = N - 1;                                        \
            const unsigned short* src = B + (size_t)brow * ldb + k0 + scol;        \
            async_copy16(src, &Bl[pB*2048 + wv*512]);                              \
        }                                                                          \
        __syncthreads();                                                           \
        short8 af[4], bf[4];                                                       \
        _Pragma("unroll")                                                          \
        for (int i = 0; i < 4; ++i) {                                              \
            af[i] = *(const short8*)&Al[(wrow + i*16 + lq)*32 + quad*8];           \
            bf[i] = *(const short8*)&Bl[(wcol + i*16 + lq)*32 + quad*8];           \
        }                                                                          \
        _Pragma("unroll")                                                          \
        for (int mi = 0; mi < 4; ++mi)                                             \
            _Pragma("unroll")                                                      \
            for (int ni = 0; ni < 4; ++ni)                                         \
                acc[mi][ni] = __builtin_amdgcn_mfma_f32_16x16x32_bf16(             \
                    af[mi], bf[ni], acc[mi][ni], 0, 0, 0);                         \
        __syncthreads();                                                           \
    }                                                                              \
    _Pragma("unroll")                                                              \
    for (int mi = 0; mi < 4; ++mi)                                                 \
        _Pragma("unroll")                                                          \
        for (int ni = 0; ni < 4; ++ni) {                                           \
            int col = n0 + wcol + ni*16 + lq;                                      \
            if (col < N) {                                                         \
                _Pragma("unroll")                                                  \
                for (int r = 0; r < 4; ++r)                                        \
                    STORE_STMT;                                                    \
            }                                                                      \
        }

__global__ __launch_bounds__(256, 2) void bgemm2(const unsigned short* __restrict__ A,
                                                 int lda,
                                                 const unsigned short* __restrict__ B,
                                                 int ldb,
                                                 unsigned short* __restrict__ C,
                                                 int ldc, int K, int N, int qcmode)
{
    int bx = blockIdx.x, by = blockIdx.y;
    if (qcmode == 1) {
        const int z = blockIdx.z;
        A += (size_t)(z >> 4) * S_ * (NH_*QHD_) + (z & 15) * QHD_;
        B += (size_t)(z & 15) * RANK_ * NOPE_;
        C += (size_t)z * S_ * DTOT_;
    } else if (qcmode == 2) {
        // VW^T[b,h] [128][2048] = out_absorb[h] [128][512] @ (k_cat[b][:, :512])^T
        const int z = blockIdx.z;
        A += (size_t)(z & 15) * 256 * RANK_ + (size_t)NOPE_ * RANK_;
        B += (size_t)(z >> 4) * S_ * DTOT_;
        C += (size_t)z * VDIM_ * S_;
    } else {
        XCD_SWZ(bx, by);
    }
    BGEMM_BODY(C[(size_t)(m0 + wrow + mi*16 + quad*4 + r) * ldc + col] = f2bf(acc[mi][ni][r]))
}

// ---------------------------------------------------------------------------
// gemm256: 256x256 tile, 8 waves (512 thr), BK=64, double-buffered 128KB LDS,
// 4-phase/tile schedule with COUNTED vmcnt (T3+T4): loads stay in flight
// across raw s_barriers; vmcnt(4) once per tile, never 0 in steady state.
// LDS granule-XOR swizzle (g ^ (row&7)) -> conflict-free ds_read_b128
// (same algebra proven in flash sKa this session).
// Requires M%256==0, N%256==0, K%64==0, K>=128. C = A[M][K] @ Bt^T, Bt [N][K].
// Phase map (tile u): ph0{read a0-3,b0-1; stage A1(u+1); mfma rf0-3 x nf0-1}
//   ph1{read b2-3; stage B1(u+1); mfma rf0-3 x nf2-3}
//   ph2{read a4-7; stage B0(u+2); mfma rf4-7 x nf0-1}
//   ph3{stage A0(u+2); mfma rf4-7 x nf2-3; vmcnt(4|0)}
// Invariants: A-quarters of a buffer free after ph2 of their tile, B after
// ph1; tile t's 8 loads issued at ph2/ph3(t-2), ph0/ph1(t-1); vmcnt(4) at
// ph3(t-1) (4 younger loads in flight) guarantees tile t landed.
// ---------------------------------------------------------------------------
#define PHASE_BAR() { __builtin_amdgcn_sched_barrier(0);                           \
    asm volatile("" ::: "memory");                                                 \
    __builtin_amdgcn_s_barrier();                                                  \
    asm volatile("" ::: "memory");                                                 \
    __builtin_amdgcn_sched_barrier(0); }

#define STG_A(Q, TT) {                                                             \
    const unsigned short* s_ = A + (size_t)(m0 + (Q)*128) * lda + (TT)*64 + stA;   \
    async_copy16(s_,                  &sA[((TT)&1)*16384 + (Q)*8192 + wid*512]);   \
    async_copy16(s_ + (size_t)64*lda, &sA[((TT)&1)*16384 + (Q)*8192 + 4096 + wid*512]); }
#define STG_B(Q, TT) {                                                             \
    const unsigned short* s_ = B + (size_t)(n0 + (Q)*128) * ldb + (TT)*64 + stB;   \
    async_copy16(s_,                  &sB[((TT)&1)*16384 + (Q)*8192 + wid*512]);   \
    async_copy16(s_ + (size_t)64*ldb, &sB[((TT)&1)*16384 + (Q)*8192 + 4096 + wid*512]); }

#define G256_BODY(STORE_STMT)                                                      \
    __shared__ unsigned short sA[2*16384];                                         \
    __shared__ unsigned short sB[2*16384];                                         \
    const int t    = threadIdx.x;                                                  \
    const int wid  = t >> 6;                                                       \
    const int lane = t & 63;                                                       \
    const int lq = lane & 15, quad = lane >> 4;                                    \
    const int wm = wid >> 2, wn = wid & 3;                                         \
    int bx = blockIdx.x, by = blockIdx.y;                                          \
    XCD_SWZ(bx, by);                                                               \
    const int m0 = by * 256, n0 = bx * 256;                                        \
    const int nt = K >> 6;                                                         \
    const int trow = t >> 3;                                                       \
    const int gcol = ((t & 7) ^ (trow & 7)) * 8;                                   \
    const size_t stA = (size_t)trow * lda + gcol;                                  \
    const size_t stB = (size_t)trow * ldb + gcol;                                  \
    const int swz  = lq & 7;                                                       \
    const int selA = (swz >> 2) * 32;                                              \
    const int selB2 = 32 - selA;                                                   \
    const int kqo  = (quad ^ (swz & 3)) * 8;                                       \
    const int aoff = (wm*128 + lq)*64 + kqo;                                       \
    const int boff = (wn*64  + lq)*64 + kqo;                                       \
    f32x4 acc[8][4] = {};                                                          \
    /* prologue: tile0 full (8 loads) + tile1 B0,A0 (4 loads) */                   \
    STG_B(0, 0); STG_A(0, 0); STG_A(1, 0); STG_B(1, 0);                            \
    STG_B(0, 1); STG_A(0, 1);                                                      \
    asm volatile("s_waitcnt vmcnt(4)" ::: "memory");                               \
    PHASE_BAR();                                                                   \
    for (int u = 0; u < nt; ++u) {                                                 \
        const unsigned short* aB = &sA[(u & 1)*16384 + aoff];                      \
        const unsigned short* bB = &sB[(u & 1)*16384 + boff];                      \
        short8 a03[4][2], a47[4][2], b01[2][2], b23[2][2];                         \
        /* ---- ph0 ---- */                                                        \
        _Pragma("unroll")                                                          \
        for (int rf = 0; rf < 4; ++rf) {                                           \
            a03[rf][0] = *(const short8*)(aB + rf*1024 + selA);                    \
            a03[rf][1] = *(const short8*)(aB + rf*1024 + selB2);                   \
        }                                                                          \
        _Pragma("unroll")                                                          \
        for (int nf = 0; nf < 2; ++nf) {                                           \
            b01[nf][0] = *(const short8*)(bB + nf*1024 + selA);                    \
            b01[nf][1] = *(const short8*)(bB + nf*1024 + selB2);                   \
        }                                                                          \
        if (u + 1 < nt) { STG_A(1, u + 1); }                                       \
        _Pragma("unroll")                                                          \
        for (int rf = 0; rf < 4; ++rf)                                             \
            _Pragma("unroll")                                                      \
            for (int nf = 0; nf < 2; ++nf) {                                       \
                acc[rf][nf] = __builtin_amdgcn_mfma_f32_16x16x32_bf16(             \
                    a03[rf][0], b01[nf][0], acc[rf][nf], 0, 0, 0);                 \
                acc[rf][nf] = __builtin_amdgcn_mfma_f32_16x16x32_bf16(             \
                    a03[rf][1], b01[nf][1], acc[rf][nf], 0, 0, 0);                 \
            }                                                                      \
        PHASE_BAR();                                                               \
        /* ---- ph1 ---- */                                                        \
        _Pragma("unroll")                                                          \
        for (int nf = 0; nf < 2; ++nf) {                                           \
            b23[nf][0] = *(const short8*)(bB + (2 + nf)*1024 + selA);              \
            b23[nf][1] = *(const short8*)(bB + (2 + nf)*1024 + selB2);             \
        }                                                                          \
        if (u + 1 < nt) { STG_B(1, u + 1); }                                       \
        _Pragma("unroll")                                                          \
        for (int rf = 0; rf < 4; ++rf)                                             \
            _Pragma("unroll")                                                      \
            for (int nf = 0; nf < 2; ++nf) {                                       \
                acc[rf][2 + nf] = __builtin_amdgcn_mfma_f32_16x16x32_bf16(         \
                    a03[rf][0], b23[nf][0], acc[rf][2 + nf], 0, 0, 0);             \
                acc[rf][2 + nf] = __builtin_amdgcn_mfma_f32_16x16x32_bf16(         \
                    a03[rf][1], b23[nf][1], acc[rf][2 + nf], 0, 0, 0);             \
            }                                                                      \
        PHASE_BAR();                                                               \
        /* ---- ph2 ---- */                                                        \
        _Pragma("unroll")                                                          \
        for (int rf = 0; rf < 4; ++rf) {                                           \
            a47[rf][0] = *(const short8*)(aB + (4 + rf)*1024 + selA);              \
            a47[rf][1] = *(const short8*)(aB + (4 + rf)*1024 + selB2);             \
        }                                                                          \
        if (u + 2 < nt) { STG_B(0, u + 2); }                                       \
        _Pragma("unroll")                                                          \
        for (int rf = 0; rf < 4; ++rf)                                             \
            _Pragma("unroll")                                                      \
            for (int nf = 0; nf < 2; ++nf) {                                       \
                acc[4 + rf][nf] = __builtin_amdgcn_mfma_f32_16x16x32_bf16(         \
                    a47[rf][0], b01[nf][0], acc[4 + rf][nf], 0, 0, 0);             \
                acc[4 + rf][nf] = __builtin_amdgcn_mfma_f32_16x16x32_bf16(         \
                    a47[rf][1], b01[nf][1], acc[4 + rf][nf], 0, 0, 0);             \
            }                                                                      \
        PHASE_BAR();                                                               \
        /* ---- ph3 ---- */                                                        \
        if (u + 2 < nt) { STG_A(0, u + 2); }                                       \
        _Pragma("unroll")                                                          \
        for (int rf = 0; rf < 4; ++rf)                                             \
            _Pragma("unroll")                                                      \
            for (int nf = 0; nf < 2; ++nf) {                                       \
                acc[4 + rf][2 + nf] = __builtin_amdgcn_mfma_f32_16x16x32_bf16(     \
                    a47[rf][0], b23[nf][0], acc[4 + rf][2 + nf], 0, 0, 0);         \
                acc[4 + rf][2 + nf] = __builtin_amdgcn_mfma_f32_16x16x32_bf16(     \
                    a47[rf][1], b23[nf][1], acc[4 + rf][2 + nf], 0, 0, 0);         \
            }                                                                      \
        if (u + 2 < nt) { asm volatile("s_waitcnt vmcnt(4)" ::: "memory"); }       \
        else            { asm volatile("s_waitcnt vmcnt(0)" ::: "memory"); }       \
        PHASE_BAR();                                                               \
    }                                                                              \
    _Pragma("unroll")                                                              \
    for (int rf = 0; rf < 8; ++rf)                                                 \
        _Pragma("unroll")                                                          \
        for (int nf = 0; nf < 4; ++nf) {                                           \
            const size_t rb = (size_t)(m0 + wm*128 + rf*16 + quad*4) * ldc         \
                              + n0 + wn*64 + nf*16 + lq;                           \
            _Pragma("unroll")                                                      \
            for (int r = 0; r < 4; ++r)                                            \
                STORE_STMT;                                                        \
        }

__global__ __launch_bounds__(512, 2) void gemm256(const unsigned short* __restrict__ A,
                                                  int lda,
                                                  const unsigned short* __restrict__ B,
                                                  int ldb,
                                                  unsigned short* __restrict__ C,
                                                  int ldc, int K)
{
    G256_BODY(C[rb + (size_t)r*ldc] = f2bf(acc[rf][nf][r]))
}

__global__ __launch_bounds__(512, 2) void gemm256f(const unsigned short* __restrict__ A,
                                                   int lda,
                                                   const unsigned short* __restrict__ B,
                                                   int ldb,
                                                   float* __restrict__ C,
                                                   int ldc, int K)
{
    G256_BODY(C[rb + (size_t)r*ldc] = acc[rf][nf][r])
}

// ---------------------------------------------------------------------------
// Per (b,s) row: RMSNorm ckv (bf16 in) -> k_cat[0:512]; RoPE k_pe -> [512:576].
// ---------------------------------------------------------------------------
__global__ __launch_bounds__(128) void postkv(const unsigned short* __restrict__ ckv_bf,
                                              const float* __restrict__ lnw,
                                              const int*   __restrict__ pos_ids,
                                              const float* __restrict__ cosc,
                                              const float* __restrict__ sinc,
                                              unsigned short* __restrict__ k_cat)
{
    const int row = blockIdx.x;
    const int t   = threadIdx.x;
    const unsigned short* src = ckv_bf + (size_t)row * DTOT_;
    __shared__ float red[128];

    ushort4 v = *(const ushort4*)(src + t * 4);
    float x0 = bf2f(v.x), x1 = bf2f(v.y), x2 = bf2f(v.z), x3 = bf2f(v.w);
    red[t] = x0*x0 + x1*x1 + x2*x2 + x3*x3;
    __syncthreads();
    for (int off = 64; off > 0; off >>= 1) {
        if (t < off) red[t] += red[t + off];
        __syncthreads();
    }
    const float rs = rsqrtf(red[0] / (float)RANK_ + 1e-6f);

    unsigned short* kc = k_cat + (size_t)row * DTOT_;
    *(unsigned long long*)(kc + t*4) =
        pack4bf(x0*rs*lnw[t*4+0], x1*rs*lnw[t*4+1], x2*rs*lnw[t*4+2], x3*rs*lnw[t*4+3]);

    if (t < 32) {
        const int pos = pos_ids[row];
        const float c  = cosc[pos * ROPE_ + t];
        const float sn = sinc[pos * ROPE_ + t];
        const float y0 = bf2f(src[RANK_ + 2*t]);
        const float y1 = bf2f(src[RANK_ + 2*t + 1]);
        kc[RANK_ + t]      = f2bf(y0*c - y1*sn);
        kc[RANK_ + 32 + t] = f2bf(y1*c + y0*sn);
    }
}

// ---------------------------------------------------------------------------
// RoPE q_pe (bf16 in) -> q_cat[...,512:576]. grid = B*S, 512 threads.
// ---------------------------------------------------------------------------
__global__ __launch_bounds__(512) void ropeq(const unsigned short* __restrict__ q_bf,
                                             const int*   __restrict__ pos_ids,
                                             const float* __restrict__ cosc,
                                             const float* __restrict__ sinc,
                                             unsigned short* __restrict__ q_cat)
{
    const int row = blockIdx.x;
    const int t   = threadIdx.x;
    const int h   = t >> 5;
    const int i   = t & 31;
    const int pos = pos_ids[row];
    const float c  = cosc[pos * ROPE_ + i];
    const float sn = sinc[pos * ROPE_ + i];
    const unsigned short* qrow = q_bf + (size_t)row * (NH_*QHD_) + h * QHD_ + NOPE_;
    const float x0 = bf2f(qrow[2*i]);
    const float x1 = bf2f(qrow[2*i + 1]);
    const int b = row >> 11, s = row & 2047;
    unsigned short* qc = q_cat + ((size_t)(b * NH_ + h) * S_ + s) * DTOT_ + RANK_;
    qc[i]      = f2bf(x0*c - x1*sn);
    qc[32 + i] = f2bf(x1*c + x0*sn);
}

__global__ __launch_bounds__(256) void wcast(const float* __restrict__ w,
                                             unsigned short* __restrict__ wbf)
{
    const size_t i = ((size_t)blockIdx.x * 256 + threadIdx.x) * 4;
    float4 v = *(const float4*)(w + i);
    *(unsigned long long*)(wbf + i) = pack4bf(v.x, v.y, v.z, v.w);
}

// ---------------------------------------------------------------------------
// Flash attention v8 (proven 174us): absorb-V, 16 q-rows/wave, K+V DMA
// pipelined, defer-max. setprio removed (r8: +3.2% regression — lockstep
// barrier-synced waves, m190-null regime).
// ---------------------------------------------------------------------------
__device__ __forceinline__ short8 quad_transpose(unsigned d0, unsigned d1,
                                                 unsigned d2, unsigned d3,
                                                 int srcA, int srcB, bool lowquad)
{
    int e0 = __shfl((int)d0, srcA, 64);
    int e1 = __shfl((int)d1, srcA, 64);
    int e2 = __shfl((int)d2, srcA, 64);
    int e3 = __shfl((int)d3, srcA, 64);
    int f0 = __shfl((int)d0, srcB, 64);
    int f1 = __shfl((int)d1, srcB, 64);
    int f2 = __shfl((int)d2, srcB, 64);
    int f3 = __shfl((int)d3, srcB, 64);
    i4s8 u;
    u.i.x = lowquad ? e0 : e2;
    u.i.y = lowquad ? e1 : e3;
    u.i.z = lowquad ? f0 : f2;
    u.i.w = lowquad ? f1 : f3;
    return u.s;
}

__global__ __launch_bounds__(256, 2) void flash_attn4(
    const unsigned short* __restrict__ q_cat,
    const unsigned short* __restrict__ k_cat,
    const unsigned short* __restrict__ vwt,
    unsigned short* __restrict__ attn_bf)
{
    __shared__ unsigned short sKa[32*512];   // 32768 B, RANK part, swizzled
    __shared__ unsigned short sKb[32*64];    //  4096 B, RoPE part, swizzled
    __shared__ unsigned short sVW[128*32];   //  8192 B, VW^T tile, swizzled

    const int t    = threadIdx.x;
    const int wv   = t >> 6;
    const int lane = t & 63;
    const int lq   = lane & 15;
    const int quad = lane >> 4;
    const int h    = blockIdx.x;
    const int q0   = (31 - blockIdx.y) * 64;   // longest strips first
    const int b    = blockIdx.z;
    const int srcA = lq + ((quad & 1) << 5);
    const int srcB = srcA + 16;
    const bool lowq = quad < 2;
    const int myq  = q0 + wv*16 + lq;

    // Q fragments (loop-invariant)
    const unsigned short* qrow =
        q_cat + (((size_t)(b*NH_ + h)) * S_ + q0 + wv*16 + lq) * DTOT_ + quad*8;
    short8 qf[18];
#pragma unroll
    for (int c = 0; c < 18; ++c) qf[c] = *(const short8*)(qrow + c*32);

    const unsigned short* kcb = k_cat + (size_t)b * S_ * DTOT_;
    const unsigned short* vtb = vwt + (size_t)(b*NH_ + h) * VDIM_ * S_;

    f32x4 o[8];
#pragma unroll
    for (int i = 0; i < 8; ++i) o[i] = (f32x4){0.f, 0.f, 0.f, 0.f};
    float m_i = -1e30f, l_i = 0.f;
    const float scale = 0.0721687836f;  // 1/sqrt(192)
    const int ntiles = (q0 >> 5) + 2;

    // --- K read-side swizzle: logical granule (row, g) lives at physical
    // g^(row&7); rows lq and 16+lq share (lq&7).
    const int swz  = lq & 7;
    const int selA = (swz >> 2) * 32;           // shorts: +32 if bit2 of swz
    const int selB = 32 - selA;
    const int kqo  = (quad ^ (swz & 3)) * 8;    // shorts within 128B block
    const unsigned short* kr0a = &sKa[lq*512 + kqo];
    const unsigned short* kr1a = &sKa[(16 + lq)*512 + kqo];
    const unsigned short* kr0b = &sKb[lq*64 + kqo];
    const unsigned short* kr1b = &sKb[(16 + lq)*64 + kqo];

    // --- K staging per-lane offsets (3 persistent VGPRs, no division)
    const int kq0 = wv*DTOT_ + (lane ^ wv)*8;        // even p: row r=p*4+wv, r&7=wv
    const int kq1 = wv*DTOT_ + (lane ^ (wv + 4))*8;  // odd  p: r&7=wv+4
    const int kob = (t >> 3)*DTOT_ + RANK_ + ((t & 7) ^ ((t >> 3) & 7))*8;

    // V staging coords: row r = p*64 + wv*16 + (lane>>2); physical col
    // (lane&3) stores logical k-granule (lane&3)^((r>>1)&3) -> 2-way reads.
    const int vrow  = wv*16 + (lane >> 2);                       // + p*64
    const int vgcol = (((lane & 3) ^ ((lane >> 3) & 3))) * 8;    // swizzled source
    const int pvsw  = (quad ^ ((lq >> 1) & 3)) * 8;              // PV read group

#define ISSUE_K(TPTR)                                                          \
    _Pragma("unroll")                                                          \
    for (int p = 0; p < 8; ++p)                                                \
        async_copy16((TPTR) + (p*4)*DTOT_ + ((p & 1) ? kq1 : kq0),             \
                     &sKa[p*2048 + wv*512]);                                   \
    async_copy16((TPTR) + kob, &sKb[wv*512])

    const unsigned short* ktp = kcb;      // K tile pointer, +32*DTOT_ per tile
    ISSUE_K(ktp);
    ktp += 32 * DTOT_;

    for (int tt = 0; tt < ntiles; ++tt) {
        const int k0 = tt << 5;
        __syncthreads();   // barrier1: K(tt) DMA drained -> sK valid; sVW free
        {   // VW stage: 2 DMAs, hidden behind QK+softmax
#pragma unroll
            for (int p = 0; p < 2; ++p) {
                const unsigned short* vsrc =
                    vtb + (size_t)(p*64 + vrow) * S_ + k0 + vgcol;
                async_copy16(vsrc, &sVW[p*2048 + wv*512]);
            }
        }
        // QK^T (swizzled reads: per-lane base + compile-time offsets)
        f32x4 s0a = {0.f,0.f,0.f,0.f}, s0b = {0.f,0.f,0.f,0.f};
        f32x4 s1a = {0.f,0.f,0.f,0.f}, s1b = {0.f,0.f,0.f,0.f};
#pragma unroll
        for (int c = 0; c < 16; c += 2) {
            short8 ka0 = *(const short8*)(kr0a + c*32 + selA);
            short8 kb0 = *(const short8*)(kr0a + c*32 + selB);
            short8 ka1 = *(const short8*)(kr1a + c*32 + selA);
            short8 kb1 = *(const short8*)(kr1a + c*32 + selB);
            s0a = __builtin_amdgcn_mfma_f32_16x16x32_bf16(ka0, qf[c],   s0a, 0, 0, 0);
            s1a = __builtin_amdgcn_mfma_f32_16x16x32_bf16(ka1, qf[c],   s1a, 0, 0, 0);
            s0b = __builtin_amdgcn_mfma_f32_16x16x32_bf16(kb0, qf[c+1], s0b, 0, 0, 0);
            s1b = __builtin_amdgcn_mfma_f32_16x16x32_bf16(kb1, qf[c+1], s1b, 0, 0, 0);
        }
        {   // RoPE chunks (c = 16,17) from sKb
            short8 ka0 = *(const short8*)(kr0b + selA);
            short8 kb0 = *(const short8*)(kr0b + selB);
            short8 ka1 = *(const short8*)(kr1b + selA);
            short8 kb1 = *(const short8*)(kr1b + selB);
            s0a = __builtin_amdgcn_mfma_f32_16x16x32_bf16(ka0, qf[16], s0a, 0, 0, 0);
            s1a = __builtin_amdgcn_mfma_f32_16x16x32_bf16(ka1, qf[16], s1a, 0, 0, 0);
            s0b = __builtin_amdgcn_mfma_f32_16x16x32_bf16(kb0, qf[17], s0b, 0, 0, 0);
            s1b = __builtin_amdgcn_mfma_f32_16x16x32_bf16(kb1, qf[17], s1b, 0, 0, 0);
        }
        // online softmax (per-lane q-row = myq), T13 defer-max THR=8
        float sv[8];
#pragma unroll
        for (int r = 0; r < 4; ++r) {
            int kk0 = k0 + quad*4 + r;
            sv[r]     = (kk0      <= myq) ? (s0a[r] + s0b[r]) * scale : -1e30f;
            sv[r + 4] = (kk0 + 16 <= myq) ? (s1a[r] + s1b[r]) * scale : -1e30f;
        }
        float mx = sv[0];
#pragma unroll
        for (int i = 1; i < 8; ++i) mx = fmaxf(mx, sv[i]);
        mx = fmaxf(mx, __shfl_xor(mx, 16));
        mx = fmaxf(mx, __shfl_xor(mx, 32));
        if (!__all(mx <= m_i + 8.f)) {     // wave-uniform branch, rare after warmup
            const float m_new = fmaxf(m_i, mx);
            const float alpha = __expf(m_i - m_new);
            m_i = m_new;
            l_i *= alpha;
#pragma unroll
            for (int i = 0; i < 8; ++i) {
                o[i][0]*=alpha; o[i][1]*=alpha; o[i][2]*=alpha; o[i][3]*=alpha;
            }
        }
        float p[8]; float ls = 0.f;
#pragma unroll
        for (int i = 0; i < 8; ++i) { p[i] = __expf(sv[i] - m_i); ls += p[i]; }
        ls += __shfl_xor(ls, 16);
        ls += __shfl_xor(ls, 32);
        l_i += ls;
        short8 pb = quad_transpose(pack2bf(p[0], p[1]), pack2bf(p[2], p[3]),
                                   pack2bf(p[4], p[5]), pack2bf(p[6], p[7]),
                                   srcA, srcB, lowq);
        __syncthreads();   // barrier2: VW(tt) DMA drained; all QK reads of sK done
        // K(t+1) DMA: issued now, hidden under PV, drained at next barrier1
        if (tt + 1 < ntiles) {
            ISSUE_K(ktp);
            ktp += 32 * DTOT_;
        }
        // PV: o[dt] covers d = dt*16 + quad*4 + r for q-col = myq
#pragma unroll
        for (int dt = 0; dt < 8; ++dt) {
            short8 va = *(const short8*)&sVW[(dt*16 + lq)*32 + pvsw];
            o[dt] = __builtin_amdgcn_mfma_f32_16x16x32_bf16(va, pb, o[dt], 0, 0, 0);
        }
    }

    // store: transpose o (rows=d, cols=q) -> lane holds q=lq, 8 consecutive d.
    const float inv = 1.0f / l_i;
    unsigned short* orow =
        attn_bf + ((size_t)b * S_ + q0 + wv*16 + lq) * (NH_*VDIM_) + h*VDIM_;
#pragma unroll
    for (int dt2 = 0; dt2 < 4; ++dt2) {
        short8 xa = quad_transpose(
            pack2bf(o[2*dt2][0]*inv,   o[2*dt2][1]*inv),
            pack2bf(o[2*dt2][2]*inv,   o[2*dt2][3]*inv),
            pack2bf(o[2*dt2+1][0]*inv, o[2*dt2+1][1]*inv),
            pack2bf(o[2*dt2+1][2]*inv, o[2*dt2+1][3]*inv),
            srcA, srcB, lowq);
        *(short8*)(orow + dt2*32 + quad*8) = xa;
    }
}

extern "C" void kernel_launch(void* const* d_in, const int* in_sizes, int n_in,
                              void* d_out, int out_size, void* d_ws, size_t ws_size,
                              hipStream_t stream)
{
    const float* hidden  = (const float*)d_in[0];
    // d_in[1] = attention_mask (guaranteed causal tril, handled analytically)
    const int*   pos_ids = (const int*)d_in[2];
    const float* cosc    = (const float*)d_in[3];
    const float* sinc    = (const float*)d_in[4];
    const float* Wq      = (const float*)d_in[5];
    const float* Wkv_a   = (const float*)d_in[6];
    const float* lnw     = (const float*)d_in[7];
    const float* Wkv_b   = (const float*)d_in[8];
    const float* Wo      = (const float*)d_in[9];
    float* out = (float*)d_out;

    const int M = B_ * S_;  // 4096
    char* ws = (char*)d_ws;
    // Workspace layout (139.5 MB total, time-disjoint aliases):
    unsigned short* hidden_bf = (unsigned short*)ws;                 // 16.78 MB (live 1-5)
    unsigned short* vwT       = (unsigned short*)ws;                 // alias 16.78 MB (live 9-12)
    unsigned short* q_bf      = (unsigned short*)(ws + 16777216);    // 25.17 MB (live 3-11)
    unsigned short* attn_bf   = q_bf;                                // alias (live 12-14, after q_bf dead)
    unsigned short* ckv_bf    = (unsigned short*)(ws + 41943040);    // 4.72 MB (live 5-6)
    unsigned short* wqaT      = ckv_bf;                              // alias 2.10 MB (live 10-11)
    unsigned short* q_cat     = (unsigned short*)(ws + 46661632);    // 75.50 MB (live 7-12)
    unsigned short* k_cat     = (unsigned short*)(ws + 122159104);   // 4.72 MB (live 6-12)
    unsigned short* wT        = (unsigned short*)(ws + 126877696);   // 12.58 MB (WqT/WkvaT/WoT)
    unsigned short* w2bf      = (unsigned short*)(ws + 126877696 + 8388608); // 4.19 MB (live 8-9)

    // 1. hidden -> bf16
    cast_bf16<<<8192, 256, 0, stream>>>(hidden, hidden_bf);
    // 2. WqT = Wq^T bf16 [3072][2048]
    transpose_w<<<dim3(32, 48, 1), 256, 0, stream>>>(Wq, wT, H_, NH_*QHD_, 0, 0);
    // 3. q_bf = hidden @ Wq (bf16 out) — 256² 4-phase counted-vmcnt kernel
    gemm256<<<dim3(12, 16), 512, 0, stream>>>(hidden_bf, H_, wT, H_, q_bf, NH_*QHD_, H_);
    // 4. WkvaT bf16 [576][2048]
    transpose_w<<<dim3(32, 9, 1), 256, 0, stream>>>(Wkv_a, wT, H_, DTOT_, 0, 0);
    // 5. ckv_bf = hidden @ Wkv_a (bf16 out, ragged N=576)
    bgemm2<<<dim3(5, 32, 1), 256, 0, stream>>>(hidden_bf, H_, wT, H_, ckv_bf, DTOT_, H_, DTOT_, 0);
    // 6. RMSNorm + k_pe RoPE -> k_cat
    postkv<<<M, 128, 0, stream>>>(ckv_bf, lnw, pos_ids, cosc, sinc, k_cat);
    // 7. q_pe RoPE -> q_cat[...,512:576]
    ropeq<<<M, 512, 0, stream>>>(q_bf, pos_ids, cosc, sinc, q_cat);
    // 8. Wkv_b -> bf16
    wcast<<<(NH_*256*RANK_)/1024, 256, 0, stream>>>(Wkv_b, w2bf);
    // 9. vwT[b,h] = out_absorb[h] @ k_cat[b][:, :512]^T  (bf16, [128][2048] per z)
    bgemm2<<<dim3(16, 1, 32), 256, 0, stream>>>(w2bf, RANK_, k_cat, DTOT_, vwT, S_, RANK_, S_, 2);
    // 10. wqaT[h] = (Wkv_b[h][0:128])^T bf16 [512][128]
    transpose_w<<<dim3(2, 8, 16), 256, 0, stream>>>(Wkv_b, wqaT, NOPE_, RANK_,
                                                    (size_t)256*RANK_, (size_t)RANK_*NOPE_);
    // 11. q_cat[...,0:512] = q_nope @ q_absorb (batched, K=128)
    bgemm2<<<dim3(4, 16, 32), 256, 0, stream>>>(q_bf, NH_*QHD_, wqaT, NOPE_, q_cat, DTOT_, NOPE_, RANK_, 1);
    // 12. flash attention (absorb-V) -> attn_bf (bf16)
    flash_attn4<<<dim3(NH_, S_/64, B_), 256, 0, stream>>>(q_cat, k_cat, vwT, attn_bf);
    // 13. WoT bf16 [2048][2048]
    transpose_w<<<dim3(32, 32, 1), 256, 0, stream>>>(Wo, wT, H_, H_, 0, 0);
    // 14. out = attn @ Wo (f32 out) — 256² 4-phase counted-vmcnt kernel
    gemm256f<<<dim3(8, 16), 512, 0, stream>>>(attn_bf, H_, wT, H_, out, H_, H_);
}

// Round 10
// 509.493 us; speedup vs baseline: 1.6838x; 1.0185x over previous
//
#include <hip/hip_runtime.h>
#include <math.h>

#define B_    2
#define S_    2048
#define H_    2048
#define NH_   16
#define NOPE_ 128
#define ROPE_ 64
#define VDIM_ 128
#define RANK_ 512
#define QHD_  192   // NOPE + ROPE
#define DTOT_ 576   // RANK + ROPE

typedef short short8 __attribute__((ext_vector_type(8)));
typedef float f32x4 __attribute__((ext_vector_type(4)));

__device__ __forceinline__ unsigned short f2bf(float f) {
    unsigned u = __float_as_uint(f);
    u += 0x7fffu + ((u >> 16) & 1u);
    return (unsigned short)(u >> 16);
}
__device__ __forceinline__ float bf2f(unsigned short u) {
    return __uint_as_float((unsigned)u << 16);
}
__device__ __forceinline__ unsigned pack2bf(float a, float b) {
    return (unsigned)f2bf(a) | ((unsigned)f2bf(b) << 16);
}
__device__ __forceinline__ unsigned long long pack4bf(float a, float b, float c, float d) {
    return (unsigned long long)pack2bf(a, b) | ((unsigned long long)pack2bf(c, d) << 32);
}
union i4s8 { int4 i; short8 s; };

// Async global->LDS, 16B per lane. LDS dest = wave-uniform base + lane*16.
typedef __attribute__((address_space(3))) unsigned int lds_u32_t;
typedef __attribute__((address_space(1))) const unsigned int glob_u32_t;
__device__ __forceinline__ void async_copy16(const unsigned short* g, unsigned short* l) {
    __builtin_amdgcn_global_load_lds((glob_u32_t*)g, (lds_u32_t*)l, 16, 0, 0);
}

// ---------------------------------------------------------------------------
// cast fp32 -> bf16, 4 elems/thread.
// ---------------------------------------------------------------------------
__global__ __launch_bounds__(256) void cast_bf16(const float* __restrict__ in,
                                                 unsigned short* __restrict__ out)
{
    const size_t i = ((size_t)blockIdx.x * 256 + threadIdx.x) * 4;
    float4 v = *(const float4*)(in + i);
    *(unsigned long long*)(out + i) = pack4bf(v.x, v.y, v.z, v.w);
}

// ---------------------------------------------------------------------------
// Transpose + cast: in fp32 [Rr][Cc] (batched) -> out bf16 [Cc][Rr].
// grid (Rr/64, Cc/64, batch), 256 threads.
// ---------------------------------------------------------------------------
__global__ __launch_bounds__(256) void transpose_w(const float* __restrict__ in,
                                                   unsigned short* __restrict__ out,
                                                   int Rr, int Cc,
                                                   size_t inBatch, size_t outBatch)
{
    __shared__ unsigned short tl[64][72];
    in  += (size_t)blockIdx.z * inBatch;
    out += (size_t)blockIdx.z * outBatch;
    const int t  = threadIdx.x;
    const int r0 = blockIdx.x * 64;
    const int c0 = blockIdx.y * 64;
    const int lr = t >> 4;
    const int lc = (t & 15) * 4;
#pragma unroll
    for (int r = 0; r < 4; ++r) {
        float4 v = *(const float4*)(in + (size_t)(r0 + lr*4 + r) * Cc + c0 + lc);
        tl[lr*4 + r][lc+0] = f2bf(v.x); tl[lr*4 + r][lc+1] = f2bf(v.y);
        tl[lr*4 + r][lc+2] = f2bf(v.z); tl[lr*4 + r][lc+3] = f2bf(v.w);
    }
    __syncthreads();
#pragma unroll
    for (int r = 0; r < 4; ++r) {
        ushort4 v;
        v.x = tl[lc+0][lr*4+r]; v.y = tl[lc+1][lr*4+r];
        v.z = tl[lc+2][lr*4+r]; v.w = tl[lc+3][lr*4+r];
        *(ushort4*)(out + (size_t)(c0 + lr*4 + r) * Rr + r0 + lc) = v;
    }
}

// T1 bijective XCD swizzle (requires nwg % 8 == 0).
#define XCD_SWZ(BX, BY)                                                            \
    {                                                                              \
        const int nx = gridDim.x;                                                  \
        const int nwg = nx * gridDim.y;                                            \
        const int wg = BY * nx + BX;                                               \
        const int nw = (wg & 7) * (nwg >> 3) + (wg >> 3);                          \
        BX = nw % nx; BY = nw / nx;                                                \
    }

// ---------------------------------------------------------------------------
// bf16 MFMA GEMM, m97-style: C = A[M][K](lda) @ Bt^T, Bt bf16 [N][K](ldb).
// 128x128 tile, 4 waves, BK=32, global_load_lds staging. N-guard for ragged N.
// mode 0: plain (XCD swizzle). mode 1: batched q-absorb. mode 2: batched VW^T.
// ---------------------------------------------------------------------------
#define BGEMM_BODY(STORE_STMT)                                                     \
    __shared__ unsigned short Al[128*32];                                          \
    __shared__ unsigned short Bl[128*32];                                          \
    const int t = threadIdx.x;                                                     \
    const int wv = t >> 6;                                                         \
    const int lane = t & 63;                                                       \
    const int lq = lane & 15, quad = lane >> 4;                                    \
    const int m0 = by * 128, n0 = bx * 128;                                        \
    const int wrow = (wv >> 1) * 64, wcol = (wv & 1) * 64;                         \
    const int srow = lane >> 2;                                                    \
    const int scol = (lane & 3) * 8;                                               \
    f32x4 acc[4][4] = {};                                                          \
    for (int k0 = 0; k0 < K; k0 += 32) {                                           \
        _Pragma("unroll")                                                          \
        for (int pA = 0; pA < 2; ++pA) {                                           \
            const unsigned short* src =                                            \
                A + (size_t)(m0 + pA*64 + wv*16 + srow) * lda + k0 + scol;         \
            async_copy16(src, &Al[pA*2048 + wv*512]);                              \
        }                                                                          \
        _Pragma("unroll")                                                          \
        for (int pB = 0; pB < 2; ++pB) {                                           \
            int brow = n0 + pB*64 + wv*16 + srow;                                  \
            if (brow > N - 1) brow = N - 1;                                        \
            const unsigned short* src = B + (size_t)brow * ldb + k0 + scol;        \
            async_copy16(src, &Bl[pB*2048 + wv*512]);                              \
        }                                                                          \
        __syncthreads();                                                           \
        short8 af[4], bf[4];                                                       \
        _Pragma("unroll")                                                          \
        for (int i = 0; i < 4; ++i) {                                              \
            af[i] = *(const short8*)&Al[(wrow + i*16 + lq)*32 + quad*8];           \
            bf[i] = *(const short8*)&Bl[(wcol + i*16 + lq)*32 + quad*8];           \
        }                                                                          \
        _Pragma("unroll")                                                          \
        for (int mi = 0; mi < 4; ++mi)                                             \
            _Pragma("unroll")                                                      \
            for (int ni = 0; ni < 4; ++ni)                                         \
                acc[mi][ni] = __builtin_amdgcn_mfma_f32_16x16x32_bf16(             \
                    af[mi], bf[ni], acc[mi][ni], 0, 0, 0);                         \
        __syncthreads();                                                           \
    }                                                                              \
    _Pragma("unroll")                                                              \
    for (int mi = 0; mi < 4; ++mi)                                                 \
        _Pragma("unroll")                                                          \
        for (int ni = 0; ni < 4; ++ni) {                                           \
            int col = n0 + wcol + ni*16 + lq;                                      \
            if (col < N) {                                                         \
                _Pragma("unroll")                                                  \
                for (int r = 0; r < 4; ++r)                                        \
                    STORE_STMT;                                                    \
            }                                                                      \
        }

__global__ __launch_bounds__(256, 2) void bgemm2(const unsigned short* __restrict__ A,
                                                 int lda,
                                                 const unsigned short* __restrict__ B,
                                                 int ldb,
                                                 unsigned short* __restrict__ C,
                                                 int ldc, int K, int N, int qcmode)
{
    int bx = blockIdx.x, by = blockIdx.y;
    if (qcmode == 1) {
        const int z = blockIdx.z;
        A += (size_t)(z >> 4) * S_ * (NH_*QHD_) + (z & 15) * QHD_;
        B += (size_t)(z & 15) * RANK_ * NOPE_;
        C += (size_t)z * S_ * DTOT_;
    } else if (qcmode == 2) {
        // VW^T[b,h] [128][2048] = out_absorb[h] [128][512] @ (k_cat[b][:, :512])^T
        const int z = blockIdx.z;
        A += (size_t)(z & 15) * 256 * RANK_ + (size_t)NOPE_ * RANK_;
        B += (size_t)(z >> 4) * S_ * DTOT_;
        C += (size_t)z * VDIM_ * S_;
    } else {
        XCD_SWZ(bx, by);
    }
    BGEMM_BODY(C[(size_t)(m0 + wrow + mi*16 + quad*4 + r) * ldc + col] = f2bf(acc[mi][ni][r]))
}

// ---------------------------------------------------------------------------
// gemm256: 256x256 tile, 8 waves (512 thr), BK=64, double-buffered 128KB LDS,
// 4-phase/tile schedule with COUNTED vmcnt (T3+T4) + T5 setprio around MFMA
// clusters (phase-split schedule, 1 block/CU, 8 waves at diverse roles =
// m218b regime where setprio pays +21-25%).
// ---------------------------------------------------------------------------
#define PHASE_BAR() { __builtin_amdgcn_sched_barrier(0);                           \
    asm volatile("" ::: "memory");                                                 \
    __builtin_amdgcn_s_barrier();                                                  \
    asm volatile("" ::: "memory");                                                 \
    __builtin_amdgcn_sched_barrier(0); }

#define STG_A(Q, TT) {                                                             \
    const unsigned short* s_ = A + (size_t)(m0 + (Q)*128) * lda + (TT)*64 + stA;   \
    async_copy16(s_,                  &sA[((TT)&1)*16384 + (Q)*8192 + wid*512]);   \
    async_copy16(s_ + (size_t)64*lda, &sA[((TT)&1)*16384 + (Q)*8192 + 4096 + wid*512]); }
#define STG_B(Q, TT) {                                                             \
    const unsigned short* s_ = B + (size_t)(n0 + (Q)*128) * ldb + (TT)*64 + stB;   \
    async_copy16(s_,                  &sB[((TT)&1)*16384 + (Q)*8192 + wid*512]);   \
    async_copy16(s_ + (size_t)64*ldb, &sB[((TT)&1)*16384 + (Q)*8192 + 4096 + wid*512]); }

#define G256_BODY(STORE_STMT)                                                      \
    __shared__ unsigned short sA[2*16384];                                         \
    __shared__ unsigned short sB[2*16384];                                         \
    const int t    = threadIdx.x;                                                  \
    const int wid  = t >> 6;                                                       \
    const int lane = t & 63;                                                       \
    const int lq = lane & 15, quad = lane >> 4;                                    \
    const int wm = wid >> 2, wn = wid & 3;                                         \
    int bx = blockIdx.x, by = blockIdx.y;                                          \
    XCD_SWZ(bx, by);                                                               \
    const int m0 = by * 256, n0 = bx * 256;                                        \
    const int nt = K >> 6;                                                         \
    const int trow = t >> 3;                                                       \
    const int gcol = ((t & 7) ^ (trow & 7)) * 8;                                   \
    const size_t stA = (size_t)trow * lda + gcol;                                  \
    const size_t stB = (size_t)trow * ldb + gcol;                                  \
    const int swz  = lq & 7;                                                       \
    const int selA = (swz >> 2) * 32;                                              \
    const int selB2 = 32 - selA;                                                   \
    const int kqo  = (quad ^ (swz & 3)) * 8;                                       \
    const int aoff = (wm*128 + lq)*64 + kqo;                                       \
    const int boff = (wn*64  + lq)*64 + kqo;                                       \
    f32x4 acc[8][4] = {};                                                          \
    /* prologue: tile0 full (8 loads) + tile1 B0,A0 (4 loads) */                   \
    STG_B(0, 0); STG_A(0, 0); STG_A(1, 0); STG_B(1, 0);                            \
    STG_B(0, 1); STG_A(0, 1);                                                      \
    asm volatile("s_waitcnt vmcnt(4)" ::: "memory");                               \
    PHASE_BAR();                                                                   \
    for (int u = 0; u < nt; ++u) {                                                 \
        const unsigned short* aB = &sA[(u & 1)*16384 + aoff];                      \
        const unsigned short* bB = &sB[(u & 1)*16384 + boff];                      \
        short8 a03[4][2], a47[4][2], b01[2][2], b23[2][2];                         \
        /* ---- ph0 ---- */                                                        \
        _Pragma("unroll")                                                          \
        for (int rf = 0; rf < 4; ++rf) {                                           \
            a03[rf][0] = *(const short8*)(aB + rf*1024 + selA);                    \
            a03[rf][1] = *(const short8*)(aB + rf*1024 + selB2);                   \
        }                                                                          \
        _Pragma("unroll")                                                          \
        for (int nf = 0; nf < 2; ++nf) {                                           \
            b01[nf][0] = *(const short8*)(bB + nf*1024 + selA);                    \
            b01[nf][1] = *(const short8*)(bB + nf*1024 + selB2);                   \
        }                                                                          \
        if (u + 1 < nt) { STG_A(1, u + 1); }                                       \
        __builtin_amdgcn_s_setprio(1);                                             \
        _Pragma("unroll")                                                          \
        for (int rf = 0; rf < 4; ++rf)                                             \
            _Pragma("unroll")                                                      \
            for (int nf = 0; nf < 2; ++nf) {                                       \
                acc[rf][nf] = __builtin_amdgcn_mfma_f32_16x16x32_bf16(             \
                    a03[rf][0], b01[nf][0], acc[rf][nf], 0, 0, 0);                 \
                acc[rf][nf] = __builtin_amdgcn_mfma_f32_16x16x32_bf16(             \
                    a03[rf][1], b01[nf][1], acc[rf][nf], 0, 0, 0);                 \
            }                                                                      \
        __builtin_amdgcn_s_setprio(0);                                             \
        PHASE_BAR();                                                               \
        /* ---- ph1 ---- */                                                        \
        _Pragma("unroll")                                                          \
        for (int nf = 0; nf < 2; ++nf) {                                           \
            b23[nf][0] = *(const short8*)(bB + (2 + nf)*1024 + selA);              \
            b23[nf][1] = *(const short8*)(bB + (2 + nf)*1024 + selB2);             \
        }                                                                          \
        if (u + 1 < nt) { STG_B(1, u + 1); }                                       \
        __builtin_amdgcn_s_setprio(1);                                             \
        _Pragma("unroll")                                                          \
        for (int rf = 0; rf < 4; ++rf)                                             \
            _Pragma("unroll")                                                      \
            for (int nf = 0; nf < 2; ++nf) {                                       \
                acc[rf][2 + nf] = __builtin_amdgcn_mfma_f32_16x16x32_bf16(         \
                    a03[rf][0], b23[nf][0], acc[rf][2 + nf], 0, 0, 0);             \
                acc[rf][2 + nf] = __builtin_amdgcn_mfma_f32_16x16x32_bf16(         \
                    a03[rf][1], b23[nf][1], acc[rf][2 + nf], 0, 0, 0);             \
            }                                                                      \
        __builtin_amdgcn_s_setprio(0);                                             \
        PHASE_BAR();                                                               \
        /* ---- ph2 ---- */                                                        \
        _Pragma("unroll")                                                          \
        for (int rf = 0; rf < 4; ++rf) {                                           \
            a47[rf][0] = *(const short8*)(aB + (4 + rf)*1024 + selA);              \
            a47[rf][1] = *(const short8*)(aB + (4 + rf)*1024 + selB2);             \
        }                                                                          \
        if (u + 2 < nt) { STG_B(0, u + 2); }                                       \
        __builtin_amdgcn_s_setprio(1);                                             \
        _Pragma("unroll")                                                          \
        for (int rf = 0; rf < 4; ++rf)                                             \
            _Pragma("unroll")                                                      \
            for (int nf = 0; nf < 2; ++nf) {                                       \
                acc[4 + rf][nf] = __builtin_amdgcn_mfma_f32_16x16x32_bf16(         \
                    a47[rf][0], b01[nf][0], acc[4 + rf][nf], 0, 0, 0);             \
                acc[4 + rf][nf] = __builtin_amdgcn_mfma_f32_16x16x32_bf16(         \
                    a47[rf][1], b01[nf][1], acc[4 + rf][nf], 0, 0, 0);             \
            }                                                                      \
        __builtin_amdgcn_s_setprio(0);                                             \
        PHASE_BAR();                                                               \
        /* ---- ph3 ---- */                                                        \
        if (u + 2 < nt) { STG_A(0, u + 2); }                                       \
        __builtin_amdgcn_s_setprio(1);                                             \
        _Pragma("unroll")                                                          \
        for (int rf = 0; rf < 4; ++rf)                                             \
            _Pragma("unroll")                                                      \
            for (int nf = 0; nf < 2; ++nf) {                                       \
                acc[4 + rf][2 + nf] = __builtin_amdgcn_mfma_f32_16x16x32_bf16(     \
                    a47[rf][0], b23[nf][0], acc[4 + rf][2 + nf], 0, 0, 0);         \
                acc[4 + rf][2 + nf] = __builtin_amdgcn_mfma_f32_16x16x32_bf16(     \
                    a47[rf][1], b23[nf][1], acc[4 + rf][2 + nf], 0, 0, 0);         \
            }                                                                      \
        __builtin_amdgcn_s_setprio(0);                                             \
        if (u + 2 < nt) { asm volatile("s_waitcnt vmcnt(4)" ::: "memory"); }       \
        else            { asm volatile("s_waitcnt vmcnt(0)" ::: "memory"); }       \
        PHASE_BAR();                                                               \
    }                                                                              \
    _Pragma("unroll")                                                              \
    for (int rf = 0; rf < 8; ++rf)                                                 \
        _Pragma("unroll")                                                          \
        for (int nf = 0; nf < 4; ++nf) {                                           \
            const size_t rb = (size_t)(m0 + wm*128 + rf*16 + quad*4) * ldc         \
                              + n0 + wn*64 + nf*16 + lq;                           \
            _Pragma("unroll")                                                      \
            for (int r = 0; r < 4; ++r)                                            \
                STORE_STMT;                                                        \
        }

__global__ __launch_bounds__(512, 2) void gemm256(const unsigned short* __restrict__ A,
                                                  int lda,
                                                  const unsigned short* __restrict__ B,
                                                  int ldb,
                                                  unsigned short* __restrict__ C,
                                                  int ldc, int K)
{
    G256_BODY(C[rb + (size_t)r*ldc] = f2bf(acc[rf][nf][r]))
}

// ---------------------------------------------------------------------------
// g256x128f: 256x128 tile (BM=256, BN=128), 8 waves (4Mx2N, 64x64/wave),
// BK=64, 96KB dbuf LDS, 4-phase counted-vmcnt + setprio. Built for step 14
// (M=4096, N=2048): grid 16x16 = 256 blocks = exactly 1 block/CU — round-9's
// gemm256f ran this shape at 128 blocks (HALF the chip idle).
// Schedule per tile u: 6 loads for tile u+2 spread ph2 (B, free after ph1-bar)
// and ph3 (A halves, free after ph2-bar); vmcnt(6) at ph3 = wait tile u+1.
// ---------------------------------------------------------------------------
__global__ __launch_bounds__(512, 2) void g256x128f(const unsigned short* __restrict__ A,
                                                    int lda,
                                                    const unsigned short* __restrict__ B,
                                                    int ldb,
                                                    float* __restrict__ C,
                                                    int ldc, int K)
{
    __shared__ unsigned short sA[2*16384];   // 2 x 256x64
    __shared__ unsigned short sB[2*8192];    // 2 x 128x64
    const int t    = threadIdx.x;
    const int wid  = t >> 6;
    const int lane = t & 63;
    const int lq = lane & 15, quad = lane >> 4;
    const int wm = wid >> 1, wn = wid & 1;   // 4M x 2N waves
    int bx = blockIdx.x, by = blockIdx.y;
    XCD_SWZ(bx, by);
    const int m0 = by * 256, n0 = bx * 128;
    const int nt = K >> 6;
    const int trow = t >> 3;
    const int gcol = ((t & 7) ^ (trow & 7)) * 8;
    const size_t stA = (size_t)trow * lda + gcol;
    const size_t stB = (size_t)trow * ldb + gcol;
    const int swz  = lq & 7;
    const int selA = (swz >> 2) * 32;
    const int selB2 = 32 - selA;
    const int kqo  = (quad ^ (swz & 3)) * 8;
    const int aoff = (wm*64 + lq)*64 + kqo;
    const int boff = (wn*64 + lq)*64 + kqo;
    f32x4 acc[4][4] = {};

#define STGX_A(Q, TT) {                                                            \
    const unsigned short* s_ = A + (size_t)(m0 + (Q)*128) * lda + (TT)*64 + stA;   \
    async_copy16(s_,                  &sA[((TT)&1)*16384 + (Q)*8192 + wid*512]);   \
    async_copy16(s_ + (size_t)64*lda, &sA[((TT)&1)*16384 + (Q)*8192 + 4096 + wid*512]); }
#define STGX_B(TT) {                                                               \
    const unsigned short* s_ = B + (size_t)n0 * ldb + (TT)*64 + stB;               \
    async_copy16(s_,                  &sB[((TT)&1)*8192 + wid*512]);               \
    async_copy16(s_ + (size_t)64*ldb, &sB[((TT)&1)*8192 + 4096 + wid*512]); }

    // prologue: tiles 0 and 1 fully staged (12 loads); wait tile0 (6 oldest)
    STGX_B(0); STGX_A(0, 0); STGX_A(1, 0);
    STGX_B(1); STGX_A(0, 1); STGX_A(1, 1);
    asm volatile("s_waitcnt vmcnt(6)" ::: "memory");
    PHASE_BAR();
    for (int u = 0; u < nt; ++u) {
        const unsigned short* aB = &sA[(u & 1)*16384 + aoff];
        const unsigned short* bB = &sB[(u & 1)*8192 + boff];
        short8 a01[2][2], a23[2][2], b01[2][2], b23[2][2];
        // ---- ph0: read a01 + b01; mfma rf{0,1} x nf{0,1} ----
#pragma unroll
        for (int rf = 0; rf < 2; ++rf) {
            a01[rf][0] = *(const short8*)(aB + rf*1024 + selA);
            a01[rf][1] = *(const short8*)(aB + rf*1024 + selB2);
        }
#pragma unroll
        for (int nf = 0; nf < 2; ++nf) {
            b01[nf][0] = *(const short8*)(bB + nf*1024 + selA);
            b01[nf][1] = *(const short8*)(bB + nf*1024 + selB2);
        }
        __builtin_amdgcn_s_setprio(1);
#pragma unroll
        for (int rf = 0; rf < 2; ++rf)
#pragma unroll
            for (int nf = 0; nf < 2; ++nf) {
                acc[rf][nf] = __builtin_amdgcn_mfma_f32_16x16x32_bf16(
                    a01[rf][0], b01[nf][0], acc[rf][nf], 0, 0, 0);
                acc[rf][nf] = __builtin_amdgcn_mfma_f32_16x16x32_bf16(
                    a01[rf][1], b01[nf][1], acc[rf][nf], 0, 0, 0);
            }
        __builtin_amdgcn_s_setprio(0);
        PHASE_BAR();
        // ---- ph1: read b23; mfma rf{0,1} x nf{2,3} ----
#pragma unroll
        for (int nf = 0; nf < 2; ++nf) {
            b23[nf][0] = *(const short8*)(bB + (2 + nf)*1024 + selA);
            b23[nf][1] = *(const short8*)(bB + (2 + nf)*1024 + selB2);
        }
        __builtin_amdgcn_s_setprio(1);
#pragma unroll
        for (int rf = 0; rf < 2; ++rf)
#pragma unroll
            for (int nf = 0; nf < 2; ++nf) {
                acc[rf][2 + nf] = __builtin_amdgcn_mfma_f32_16x16x32_bf16(
                    a01[rf][0], b23[nf][0], acc[rf][2 + nf], 0, 0, 0);
                acc[rf][2 + nf] = __builtin_amdgcn_mfma_f32_16x16x32_bf16(
                    a01[rf][1], b23[nf][1], acc[rf][2 + nf], 0, 0, 0);
            }
        __builtin_amdgcn_s_setprio(0);
        PHASE_BAR();
        // ---- ph2: read a23; stage B(u+2) (B buf free after ph1 barrier);
        //           mfma rf{2,3} x nf{0,1} ----
#pragma unroll
        for (int rf = 0; rf < 2; ++rf) {
            a23[rf][0] = *(const short8*)(aB + (2 + rf)*1024 + selA);
            a23[rf][1] = *(const short8*)(aB + (2 + rf)*1024 + selB2);
        }
        if (u + 2 < nt) { STGX_B(u + 2); }
        __builtin_amdgcn_s_setprio(1);
#pragma unroll
        for (int rf = 0; rf < 2; ++rf)
#pragma unroll
            for (int nf = 0; nf < 2; ++nf) {
                acc[2 + rf][nf] = __builtin_amdgcn_mfma_f32_16x16x32_bf16(
                    a23[rf][0], b01[nf][0], acc[2 + rf][nf], 0, 0, 0);
                acc[2 + rf][nf] = __builtin_amdgcn_mfma_f32_16x16x32_bf16(
                    a23[rf][1], b01[nf][1], acc[2 + rf][nf], 0, 0, 0);
            }
        __builtin_amdgcn_s_setprio(0);
        PHASE_BAR();
        // ---- ph3: stage A(u+2) (A buf free after ph2 barrier);
        //           mfma rf{2,3} x nf{2,3}; counted vmcnt ----
        if (u + 2 < nt) { STGX_A(0, u + 2); STGX_A(1, u + 2); }
        __builtin_amdgcn_s_setprio(1);
#pragma unroll
        for (int rf = 0; rf < 2; ++rf)
#pragma unroll
            for (int nf = 0; nf < 2; ++nf) {
                acc[2 + rf][2 + nf] = __builtin_amdgcn_mfma_f32_16x16x32_bf16(
                    a23[rf][0], b23[nf][0], acc[2 + rf][2 + nf], 0, 0, 0);
                acc[2 + rf][2 + nf] = __builtin_amdgcn_mfma_f32_16x16x32_bf16(
                    a23[rf][1], b23[nf][1], acc[2 + rf][2 + nf], 0, 0, 0);
            }
        __builtin_amdgcn_s_setprio(0);
        if (u + 2 < nt) { asm volatile("s_waitcnt vmcnt(6)" ::: "memory"); }
        else            { asm volatile("s_waitcnt vmcnt(0)" ::: "memory"); }
        PHASE_BAR();
    }
#pragma unroll
    for (int rf = 0; rf < 4; ++rf)
#pragma unroll
        for (int nf = 0; nf < 4; ++nf) {
            const size_t rb = (size_t)(m0 + wm*64 + rf*16 + quad*4) * ldc
                              + n0 + wn*64 + nf*16 + lq;
#pragma unroll
            for (int r = 0; r < 4; ++r)
                C[rb + (size_t)r*ldc] = acc[rf][nf][r];
        }
}

// ---------------------------------------------------------------------------
// Per (b,s) row: RMSNorm ckv (bf16 in) -> k_cat[0:512]; RoPE k_pe -> [512:576].
// ---------------------------------------------------------------------------
__global__ __launch_bounds__(128) void postkv(const unsigned short* __restrict__ ckv_bf,
                                              const float* __restrict__ lnw,
                                              const int*   __restrict__ pos_ids,
                                              const float* __restrict__ cosc,
                                              const float* __restrict__ sinc,
                                              unsigned short* __restrict__ k_cat)
{
    const int row = blockIdx.x;
    const int t   = threadIdx.x;
    const unsigned short* src = ckv_bf + (size_t)row * DTOT_;
    __shared__ float red[128];

    ushort4 v = *(const ushort4*)(src + t * 4);
    float x0 = bf2f(v.x), x1 = bf2f(v.y), x2 = bf2f(v.z), x3 = bf2f(v.w);
    red[t] = x0*x0 + x1*x1 + x2*x2 + x3*x3;
    __syncthreads();
    for (int off = 64; off > 0; off >>= 1) {
        if (t < off) red[t] += red[t + off];
        __syncthreads();
    }
    const float rs = rsqrtf(red[0] / (float)RANK_ + 1e-6f);

    unsigned short* kc = k_cat + (size_t)row * DTOT_;
    *(unsigned long long*)(kc + t*4) =
        pack4bf(x0*rs*lnw[t*4+0], x1*rs*lnw[t*4+1], x2*rs*lnw[t*4+2], x3*rs*lnw[t*4+3]);

    if (t < 32) {
        const int pos = pos_ids[row];
        const float c  = cosc[pos * ROPE_ + t];
        const float sn = sinc[pos * ROPE_ + t];
        const float y0 = bf2f(src[RANK_ + 2*t]);
        const float y1 = bf2f(src[RANK_ + 2*t + 1]);
        kc[RANK_ + t]      = f2bf(y0*c - y1*sn);
        kc[RANK_ + 32 + t] = f2bf(y1*c + y0*sn);
    }
}

// ---------------------------------------------------------------------------
// RoPE q_pe (bf16 in) -> q_cat[...,512:576]. grid = B*S, 512 threads.
// ---------------------------------------------------------------------------
__global__ __launch_bounds__(512) void ropeq(const unsigned short* __restrict__ q_bf,
                                             const int*   __restrict__ pos_ids,
                                             const float* __restrict__ cosc,
                                             const float* __restrict__ sinc,
                                             unsigned short* __restrict__ q_cat)
{
    const int row = blockIdx.x;
    const int t   = threadIdx.x;
    const int h   = t >> 5;
    const int i   = t & 31;
    const int pos = pos_ids[row];
    const float c  = cosc[pos * ROPE_ + i];
    const float sn = sinc[pos * ROPE_ + i];
    const unsigned short* qrow = q_bf + (size_t)row * (NH_*QHD_) + h * QHD_ + NOPE_;
    const float x0 = bf2f(qrow[2*i]);
    const float x1 = bf2f(qrow[2*i + 1]);
    const int b = row >> 11, s = row & 2047;
    unsigned short* qc = q_cat + ((size_t)(b * NH_ + h) * S_ + s) * DTOT_ + RANK_;
    qc[i]      = f2bf(x0*c - x1*sn);
    qc[32 + i] = f2bf(x1*c + x0*sn);
}

__global__ __launch_bounds__(256) void wcast(const float* __restrict__ w,
                                             unsigned short* __restrict__ wbf)
{
    const size_t i = ((size_t)blockIdx.x * 256 + threadIdx.x) * 4;
    float4 v = *(const float4*)(w + i);
    *(unsigned long long*)(wbf + i) = pack4bf(v.x, v.y, v.z, v.w);
}

// ---------------------------------------------------------------------------
// Flash attention v8 (proven 171us): absorb-V, 16 q-rows/wave, K+V DMA
// pipelined, defer-max. (setprio hurts here — lockstep regime, r8 A/B.)
// ---------------------------------------------------------------------------
__device__ __forceinline__ short8 quad_transpose(unsigned d0, unsigned d1,
                                                 unsigned d2, unsigned d3,
                                                 int srcA, int srcB, bool lowquad)
{
    int e0 = __shfl((int)d0, srcA, 64);
    int e1 = __shfl((int)d1, srcA, 64);
    int e2 = __shfl((int)d2, srcA, 64);
    int e3 = __shfl((int)d3, srcA, 64);
    int f0 = __shfl((int)d0, srcB, 64);
    int f1 = __shfl((int)d1, srcB, 64);
    int f2 = __shfl((int)d2, srcB, 64);
    int f3 = __shfl((int)d3, srcB, 64);
    i4s8 u;
    u.i.x = lowquad ? e0 : e2;
    u.i.y = lowquad ? e1 : e3;
    u.i.z = lowquad ? f0 : f2;
    u.i.w = lowquad ? f1 : f3;
    return u.s;
}

__global__ __launch_bounds__(256, 2) void flash_attn4(
    const unsigned short* __restrict__ q_cat,
    const unsigned short* __restrict__ k_cat,
    const unsigned short* __restrict__ vwt,
    unsigned short* __restrict__ attn_bf)
{
    __shared__ unsigned short sKa[32*512];   // 32768 B, RANK part, swizzled
    __shared__ unsigned short sKb[32*64];    //  4096 B, RoPE part, swizzled
    __shared__ unsigned short sVW[128*32];   //  8192 B, VW^T tile, swizzled

    const int t    = threadIdx.x;
    const int wv   = t >> 6;
    const int lane = t & 63;
    const int lq   = lane & 15;
    const int quad = lane >> 4;
    const int h    = blockIdx.x;
    const int q0   = (31 - blockIdx.y) * 64;   // longest strips first
    const int b    = blockIdx.z;
    const int srcA = lq + ((quad & 1) << 5);
    const int srcB = srcA + 16;
    const bool lowq = quad < 2;
    const int myq  = q0 + wv*16 + lq;

    // Q fragments (loop-invariant)
    const unsigned short* qrow =
        q_cat + (((size_t)(b*NH_ + h)) * S_ + q0 + wv*16 + lq) * DTOT_ + quad*8;
    short8 qf[18];
#pragma unroll
    for (int c = 0; c < 18; ++c) qf[c] = *(const short8*)(qrow + c*32);

    const unsigned short* kcb = k_cat + (size_t)b * S_ * DTOT_;
    const unsigned short* vtb = vwt + (size_t)(b*NH_ + h) * VDIM_ * S_;

    f32x4 o[8];
#pragma unroll
    for (int i = 0; i < 8; ++i) o[i] = (f32x4){0.f, 0.f, 0.f, 0.f};
    float m_i = -1e30f, l_i = 0.f;
    const float scale = 0.0721687836f;  // 1/sqrt(192)
    const int ntiles = (q0 >> 5) + 2;

    // --- K read-side swizzle: logical granule (row, g) lives at physical
    // g^(row&7); rows lq and 16+lq share (lq&7).
    const int swz  = lq & 7;
    const int selA = (swz >> 2) * 32;           // shorts: +32 if bit2 of swz
    const int selB = 32 - selA;
    const int kqo  = (quad ^ (swz & 3)) * 8;    // shorts within 128B block
    const unsigned short* kr0a = &sKa[lq*512 + kqo];
    const unsigned short* kr1a = &sKa[(16 + lq)*512 + kqo];
    const unsigned short* kr0b = &sKb[lq*64 + kqo];
    const unsigned short* kr1b = &sKb[(16 + lq)*64 + kqo];

    // --- K staging per-lane offsets (3 persistent VGPRs, no division)
    const int kq0 = wv*DTOT_ + (lane ^ wv)*8;        // even p: row r=p*4+wv, r&7=wv
    const int kq1 = wv*DTOT_ + (lane ^ (wv + 4))*8;  // odd  p: r&7=wv+4
    const int kob = (t >> 3)*DTOT_ + RANK_ + ((t & 7) ^ ((t >> 3) & 7))*8;

    // V staging coords: row r = p*64 + wv*16 + (lane>>2); physical col
    // (lane&3) stores logical k-granule (lane&3)^((r>>1)&3) -> 2-way reads.
    const int vrow  = wv*16 + (lane >> 2);                       // + p*64
    const int vgcol = (((lane & 3) ^ ((lane >> 3) & 3))) * 8;    // swizzled source
    const int pvsw  = (quad ^ ((lq >> 1) & 3)) * 8;              // PV read group

#define ISSUE_K(TPTR)                                                          \
    _Pragma("unroll")                                                          \
    for (int p = 0; p < 8; ++p)                                                \
        async_copy16((TPTR) + (p*4)*DTOT_ + ((p & 1) ? kq1 : kq0),             \
                     &sKa[p*2048 + wv*512]);                                   \
    async_copy16((TPTR) + kob, &sKb[wv*512])

    const unsigned short* ktp = kcb;      // K tile pointer, +32*DTOT_ per tile
    ISSUE_K(ktp);
    ktp += 32 * DTOT_;

    for (int tt = 0; tt < ntiles; ++tt) {
        const int k0 = tt << 5;
        __syncthreads();   // barrier1: K(tt) DMA drained -> sK valid; sVW free
        {   // VW stage: 2 DMAs, hidden behind QK+softmax
#pragma unroll
            for (int p = 0; p < 2; ++p) {
                const unsigned short* vsrc =
                    vtb + (size_t)(p*64 + vrow) * S_ + k0 + vgcol;
                async_copy16(vsrc, &sVW[p*2048 + wv*512]);
            }
        }
        // QK^T (swizzled reads: per-lane base + compile-time offsets)
        f32x4 s0a = {0.f,0.f,0.f,0.f}, s0b = {0.f,0.f,0.f,0.f};
        f32x4 s1a = {0.f,0.f,0.f,0.f}, s1b = {0.f,0.f,0.f,0.f};
#pragma unroll
        for (int c = 0; c < 16; c += 2) {
            short8 ka0 = *(const short8*)(kr0a + c*32 + selA);
            short8 kb0 = *(const short8*)(kr0a + c*32 + selB);
            short8 ka1 = *(const short8*)(kr1a + c*32 + selA);
            short8 kb1 = *(const short8*)(kr1a + c*32 + selB);
            s0a = __builtin_amdgcn_mfma_f32_16x16x32_bf16(ka0, qf[c],   s0a, 0, 0, 0);
            s1a = __builtin_amdgcn_mfma_f32_16x16x32_bf16(ka1, qf[c],   s1a, 0, 0, 0);
            s0b = __builtin_amdgcn_mfma_f32_16x16x32_bf16(kb0, qf[c+1], s0b, 0, 0, 0);
            s1b = __builtin_amdgcn_mfma_f32_16x16x32_bf16(kb1, qf[c+1], s1b, 0, 0, 0);
        }
        {   // RoPE chunks (c = 16,17) from sKb
            short8 ka0 = *(const short8*)(kr0b + selA);
            short8 kb0 = *(const short8*)(kr0b + selB);
            short8 ka1 = *(const short8*)(kr1b + selA);
            short8 kb1 = *(const short8*)(kr1b + selB);
            s0a = __builtin_amdgcn_mfma_f32_16x16x32_bf16(ka0, qf[16], s0a, 0, 0, 0);
            s1a = __builtin_amdgcn_mfma_f32_16x16x32_bf16(ka1, qf[16], s1a, 0, 0, 0);
            s0b = __builtin_amdgcn_mfma_f32_16x16x32_bf16(kb0, qf[17], s0b, 0, 0, 0);
            s1b = __builtin_amdgcn_mfma_f32_16x16x32_bf16(kb1, qf[17], s1b, 0, 0, 0);
        }
        // online softmax (per-lane q-row = myq), T13 defer-max THR=8
        float sv[8];
#pragma unroll
        for (int r = 0; r < 4; ++r) {
            int kk0 = k0 + quad*4 + r;
            sv[r]     = (kk0      <= myq) ? (s0a[r] + s0b[r]) * scale : -1e30f;
            sv[r + 4] = (kk0 + 16 <= myq) ? (s1a[r] + s1b[r]) * scale : -1e30f;
        }
        float mx = sv[0];
#pragma unroll
        for (int i = 1; i < 8; ++i) mx = fmaxf(mx, sv[i]);
        mx = fmaxf(mx, __shfl_xor(mx, 16));
        mx = fmaxf(mx, __shfl_xor(mx, 32));
        if (!__all(mx <= m_i + 8.f)) {     // wave-uniform branch, rare after warmup
            const float m_new = fmaxf(m_i, mx);
            const float alpha = __expf(m_i - m_new);
            m_i = m_new;
            l_i *= alpha;
#pragma unroll
            for (int i = 0; i < 8; ++i) {
                o[i][0]*=alpha; o[i][1]*=alpha; o[i][2]*=alpha; o[i][3]*=alpha;
            }
        }
        float p[8]; float ls = 0.f;
#pragma unroll
        for (int i = 0; i < 8; ++i) { p[i] = __expf(sv[i] - m_i); ls += p[i]; }
        ls += __shfl_xor(ls, 16);
        ls += __shfl_xor(ls, 32);
        l_i += ls;
        short8 pb = quad_transpose(pack2bf(p[0], p[1]), pack2bf(p[2], p[3]),
                                   pack2bf(p[4], p[5]), pack2bf(p[6], p[7]),
                                   srcA, srcB, lowq);
        __syncthreads();   // barrier2: VW(tt) DMA drained; all QK reads of sK done
        // K(t+1) DMA: issued now, hidden under PV, drained at next barrier1
        if (tt + 1 < ntiles) {
            ISSUE_K(ktp);
            ktp += 32 * DTOT_;
        }
        // PV: o[dt] covers d = dt*16 + quad*4 + r for q-col = myq
#pragma unroll
        for (int dt = 0; dt < 8; ++dt) {
            short8 va = *(const short8*)&sVW[(dt*16 + lq)*32 + pvsw];
            o[dt] = __builtin_amdgcn_mfma_f32_16x16x32_bf16(va, pb, o[dt], 0, 0, 0);
        }
    }

    // store: transpose o (rows=d, cols=q) -> lane holds q=lq, 8 consecutive d.
    const float inv = 1.0f / l_i;
    unsigned short* orow =
        attn_bf + ((size_t)b * S_ + q0 + wv*16 + lq) * (NH_*VDIM_) + h*VDIM_;
#pragma unroll
    for (int dt2 = 0; dt2 < 4; ++dt2) {
        short8 xa = quad_transpose(
            pack2bf(o[2*dt2][0]*inv,   o[2*dt2][1]*inv),
            pack2bf(o[2*dt2][2]*inv,   o[2*dt2][3]*inv),
            pack2bf(o[2*dt2+1][0]*inv, o[2*dt2+1][1]*inv),
            pack2bf(o[2*dt2+1][2]*inv, o[2*dt2+1][3]*inv),
            srcA, srcB, lowq);
        *(short8*)(orow + dt2*32 + quad*8) = xa;
    }
}

extern "C" void kernel_launch(void* const* d_in, const int* in_sizes, int n_in,
                              void* d_out, int out_size, void* d_ws, size_t ws_size,
                              hipStream_t stream)
{
    const float* hidden  = (const float*)d_in[0];
    // d_in[1] = attention_mask (guaranteed causal tril, handled analytically)
    const int*   pos_ids = (const int*)d_in[2];
    const float* cosc    = (const float*)d_in[3];
    const float* sinc    = (const float*)d_in[4];
    const float* Wq      = (const float*)d_in[5];
    const float* Wkv_a   = (const float*)d_in[6];
    const float* lnw     = (const float*)d_in[7];
    const float* Wkv_b   = (const float*)d_in[8];
    const float* Wo      = (const float*)d_in[9];
    float* out = (float*)d_out;

    const int M = B_ * S_;  // 4096
    char* ws = (char*)d_ws;
    // Workspace layout (139.5 MB total, time-disjoint aliases):
    unsigned short* hidden_bf = (unsigned short*)ws;                 // 16.78 MB (live 1-5)
    unsigned short* vwT       = (unsigned short*)ws;                 // alias 16.78 MB (live 9-12)
    unsigned short* q_bf      = (unsigned short*)(ws + 16777216);    // 25.17 MB (live 3-11)
    unsigned short* attn_bf   = q_bf;                                // alias (live 12-14, after q_bf dead)
    unsigned short* ckv_bf    = (unsigned short*)(ws + 41943040);    // 4.72 MB (live 5-6)
    unsigned short* wqaT      = ckv_bf;                              // alias 2.10 MB (live 10-11)
    unsigned short* q_cat     = (unsigned short*)(ws + 46661632);    // 75.50 MB (live 7-12)
    unsigned short* k_cat     = (unsigned short*)(ws + 122159104);   // 4.72 MB (live 6-12)
    unsigned short* wT        = (unsigned short*)(ws + 126877696);   // 12.58 MB (WqT/WkvaT/WoT)
    unsigned short* w2bf      = (unsigned short*)(ws + 126877696 + 8388608); // 4.19 MB (live 8-9)

    // 1. hidden -> bf16
    cast_bf16<<<8192, 256, 0, stream>>>(hidden, hidden_bf);
    // 2. WqT = Wq^T bf16 [3072][2048]
    transpose_w<<<dim3(32, 48, 1), 256, 0, stream>>>(Wq, wT, H_, NH_*QHD_, 0, 0);
    // 3. q_bf = hidden @ Wq (bf16 out) — 256² 4-phase counted-vmcnt + setprio
    gemm256<<<dim3(12, 16), 512, 0, stream>>>(hidden_bf, H_, wT, H_, q_bf, NH_*QHD_, H_);
    // 4. WkvaT bf16 [576][2048]
    transpose_w<<<dim3(32, 9, 1), 256, 0, stream>>>(Wkv_a, wT, H_, DTOT_, 0, 0);
    // 5. ckv_bf = hidden @ Wkv_a (bf16 out, ragged N=576)
    bgemm2<<<dim3(5, 32, 1), 256, 0, stream>>>(hidden_bf, H_, wT, H_, ckv_bf, DTOT_, H_, DTOT_, 0);
    // 6. RMSNorm + k_pe RoPE -> k_cat
    postkv<<<M, 128, 0, stream>>>(ckv_bf, lnw, pos_ids, cosc, sinc, k_cat);
    // 7. q_pe RoPE -> q_cat[...,512:576]
    ropeq<<<M, 512, 0, stream>>>(q_bf, pos_ids, cosc, sinc, q_cat);
    // 8. Wkv_b -> bf16
    wcast<<<(NH_*256*RANK_)/1024, 256, 0, stream>>>(Wkv_b, w2bf);
    // 9. vwT[b,h] = out_absorb[h] @ k_cat[b][:, :512]^T  (bf16, [128][2048] per z)
    bgemm2<<<dim3(16, 1, 32), 256, 0, stream>>>(w2bf, RANK_, k_cat, DTOT_, vwT, S_, RANK_, S_, 2);
    // 10. wqaT[h] = (Wkv_b[h][0:128])^T bf16 [512][128]
    transpose_w<<<dim3(2, 8, 16), 256, 0, stream>>>(Wkv_b, wqaT, NOPE_, RANK_,
                                                    (size_t)256*RANK_, (size_t)RANK_*NOPE_);
    // 11. q_cat[...,0:512] = q_nope @ q_absorb (batched, K=128)
    bgemm2<<<dim3(4, 16, 32), 256, 0, stream>>>(q_bf, NH_*QHD_, wqaT, NOPE_, q_cat, DTOT_, NOPE_, RANK_, 1);
    // 12. flash attention (absorb-V) -> attn_bf (bf16)
    flash_attn4<<<dim3(NH_, S_/64, B_), 256, 0, stream>>>(q_cat, k_cat, vwT, attn_bf);
    // 13. WoT bf16 [2048][2048]
    transpose_w<<<dim3(32, 32, 1), 256, 0, stream>>>(Wo, wT, H_, H_, 0, 0);
    // 14. out = attn @ Wo (f32 out) — 256x128-tile, 256 blocks = 1/CU
    g256x128f<<<dim3(16, 16), 512, 0, stream>>>(attn_bf, H_, wT, H_, out, H_, H_);
}